// Round 8
// baseline (553.511 us; speedup 1.0000x reference)
//
#include <hip/hip_runtime.h>
#include <math.h>

#define B_   4
#define NQ_  1024
#define NK_  1024
#define D_   1024
#define H_   16
#define DH_  64
#define DFF_ 4096
#define SCALE_ (1.0f/32.0f)   // 1/sqrt(D)
#define LN_EPS_ 1e-5f

typedef __attribute__((ext_vector_type(8))) short bf16x8_t;  // 8 bf16 = 4 VGPR
typedef __attribute__((ext_vector_type(4))) float f32x4_t;

__device__ __forceinline__ ushort f2bf_rne(float x) {
    unsigned u = __float_as_uint(x);
    unsigned r = (u + 0x7FFFu + ((u >> 16) & 1u)) >> 16;
    return (ushort)r;
}
__device__ __forceinline__ float bf2f(ushort h) {
    return __uint_as_float(((unsigned)h) << 16);
}

// async global->LDS, 16B per lane. LDS dest = wave-uniform base + lane*16.
__device__ __forceinline__ void gl_lds16(const ushort* g, ushort* l) {
    __builtin_amdgcn_global_load_lds(
        (const __attribute__((address_space(1))) unsigned int*)g,
        (__attribute__((address_space(3))) unsigned int*)l, 16, 0, 0);
}

// ---------------------------------------------------------------------------
// fp32 -> (hi,lo) bf16 planes.
// ---------------------------------------------------------------------------
__global__ __launch_bounds__(256) void split_rows(const float* __restrict__ src,
        ushort* __restrict__ hi, ushort* __restrict__ lo, int n4)
{
    int i = blockIdx.x * 256 + threadIdx.x;
    if (i >= n4) return;
    float4 v = ((const float4*)src)[i];
    ushort4 h, l;
    h.x = f2bf_rne(v.x); l.x = f2bf_rne(v.x - bf2f(h.x));
    h.y = f2bf_rne(v.y); l.y = f2bf_rne(v.y - bf2f(h.y));
    h.z = f2bf_rne(v.z); l.z = f2bf_rne(v.z - bf2f(h.z));
    h.w = f2bf_rne(v.w); l.w = f2bf_rne(v.w - bf2f(h.w));
    ((ushort4*)hi)[i] = h;
    ((ushort4*)lo)[i] = l;
}

// ---------------------------------------------------------------------------
// Weight split + transpose: W[K][N] fp32 -> planes Wt[N][K] bf16.
// ---------------------------------------------------------------------------
__global__ __launch_bounds__(256) void split_tr(const float* __restrict__ Wsrc,
        ushort* __restrict__ th, ushort* __restrict__ tl, int K, int N)
{
    __shared__ float tile[32][33];
    const int nb = blockIdx.x * 32, kb = blockIdx.y * 32;
    const int t = threadIdx.x;
    {
        int r = t >> 3, c4 = (t & 7) * 4;
        float4 v = *(const float4*)&Wsrc[(size_t)(kb + r) * N + nb + c4];
        tile[r][c4 + 0] = v.x; tile[r][c4 + 1] = v.y;
        tile[r][c4 + 2] = v.z; tile[r][c4 + 3] = v.w;
    }
    __syncthreads();
    {
        int n = t >> 3, k4 = (t & 7) * 4;
        float a0 = tile[k4 + 0][n], a1 = tile[k4 + 1][n];
        float a2 = tile[k4 + 2][n], a3 = tile[k4 + 3][n];
        ushort4 h, l;
        h.x = f2bf_rne(a0); l.x = f2bf_rne(a0 - bf2f(h.x));
        h.y = f2bf_rne(a1); l.y = f2bf_rne(a1 - bf2f(h.y));
        h.z = f2bf_rne(a2); l.z = f2bf_rne(a2 - bf2f(h.z));
        h.w = f2bf_rne(a3); l.w = f2bf_rne(a3 - bf2f(h.w));
        size_t o = (size_t)(nb + n) * K + kb + k4;
        *(ushort4*)&th[o] = h;
        *(ushort4*)&tl[o] = l;
    }
}

// ---------------------------------------------------------------------------
// 2-phase dbuf MFMA GEMM (validated r7). 128^2 tile, 4 waves.
// OMODE: 0 = fp32 out, 1 = split planes out, 2 = hi-only bf16 out.
// ---------------------------------------------------------------------------
template<bool RELU, int OMODE>
__device__ __forceinline__ void gemm_body(
        const ushort* __restrict__ Ah, const ushort* __restrict__ Al,
        const ushort* __restrict__ Bh, const ushort* __restrict__ Bl,
        const float* __restrict__ bias,
        float* __restrict__ C, ushort* __restrict__ Ch, ushort* __restrict__ Cl,
        int M, int N, int Kd, int brow, int bcol)
{
    __shared__ __align__(16) ushort sAll[2][4][128 * 32];   // 64KB dbuf

    const int t    = threadIdx.x;
    const int lane = t & 63;
    const int w    = t >> 6;
    const int wr   = (w >> 1) * 64;
    const int wc   = (w & 1) * 64;

    f32x4_t acc[4][4];
    #pragma unroll
    for (int i = 0; i < 4; ++i)
        #pragma unroll
        for (int j = 0; j < 4; ++j)
            acc[i][j] = (f32x4_t){0.f, 0.f, 0.f, 0.f};

    const int fr = lane & 15;
    const int g  = lane >> 4;
    const int sS = ((g ^ ((fr >> 1) & 3)) << 3);

    const ushort* gplane = (w == 0) ? Ah : (w == 1) ? Al : (w == 2) ? Bh : Bl;
    const int     rb     = (w < 2) ? brow : bcol;
    const size_t  grow   = (size_t)(rb + (lane >> 2)) * Kd
                         + (((lane & 3) ^ ((lane >> 3) & 3)) << 3);

    {
        ushort* lp = &sAll[0][w][0];
        #pragma unroll
        for (int i = 0; i < 8; ++i)
            gl_lds16(gplane + grow + (size_t)(16 * i) * Kd, lp + i * 512);
    }
    __syncthreads();

    int cur = 0;
    for (int k0 = 0; k0 < Kd; k0 += 32) {
        if (k0 + 32 < Kd) {
            ushort* lp = &sAll[cur ^ 1][w][0];
            #pragma unroll
            for (int i = 0; i < 8; ++i)
                gl_lds16(gplane + grow + (size_t)(16 * i) * Kd + k0 + 32, lp + i * 512);
        }
        __builtin_amdgcn_sched_barrier(0);

        bf16x8_t ah[4], al[4], bh[4], bl[4];
        #pragma unroll
        for (int i = 0; i < 4; ++i) {
            int m = wr + i * 16 + fr;
            ah[i] = *(const bf16x8_t*)&sAll[cur][0][m * 32 + sS];
            al[i] = *(const bf16x8_t*)&sAll[cur][1][m * 32 + sS];
        }
        #pragma unroll
        for (int j = 0; j < 4; ++j) {
            int n = wc + j * 16 + fr;
            bh[j] = *(const bf16x8_t*)&sAll[cur][2][n * 32 + sS];
            bl[j] = *(const bf16x8_t*)&sAll[cur][3][n * 32 + sS];
        }
        #pragma unroll
        for (int i = 0; i < 4; ++i)
            #pragma unroll
            for (int j = 0; j < 4; ++j) {
                acc[i][j] = __builtin_amdgcn_mfma_f32_16x16x32_bf16(ah[i], bh[j], acc[i][j], 0, 0, 0);
                acc[i][j] = __builtin_amdgcn_mfma_f32_16x16x32_bf16(ah[i], bl[j], acc[i][j], 0, 0, 0);
                acc[i][j] = __builtin_amdgcn_mfma_f32_16x16x32_bf16(al[i], bh[j], acc[i][j], 0, 0, 0);
            }

        __syncthreads();
        cur ^= 1;
    }

    const int cl = lane & 15;
    const int rq = (lane >> 4) * 4;
    #pragma unroll
    for (int j = 0; j < 4; ++j) {
        int col = bcol + wc + j * 16 + cl;
        float bv = bias[col];
        #pragma unroll
        for (int i = 0; i < 4; ++i) {
            #pragma unroll
            for (int r = 0; r < 4; ++r) {
                int row = brow + wr + i * 16 + rq + r;
                float v = acc[i][j][r] + bv;
                if (RELU) v = fmaxf(v, 0.f);
                if (OMODE == 1) {
                    ushort h = f2bf_rne(v);
                    Ch[(size_t)row * N + col] = h;
                    Cl[(size_t)row * N + col] = f2bf_rne(v - bf2f(h));
                } else if (OMODE == 2) {
                    Ch[(size_t)row * N + col] = f2bf_rne(v);
                } else {
                    C[(size_t)row * N + col] = v;
                }
            }
        }
    }
}

// bijective XCD-chunked swizzle (nwg % 8 == 0 for all our grids)
__device__ __forceinline__ void swz_block(int& brow, int& bcol, int tile) {
    const int nx  = gridDim.x;
    const int lin = blockIdx.y * nx + blockIdx.x;
    const int cpx = (nx * gridDim.y) >> 3;
    const int swz = (lin & 7) * cpx + (lin >> 3);
    brow = (swz / nx) * tile;
    bcol = (swz % nx) * tile;
}

template<bool RELU, int OMODE>
__global__ __launch_bounds__(256) void gemm_mfma(
        const ushort* __restrict__ Ah, const ushort* __restrict__ Al,
        const ushort* __restrict__ Bh, const ushort* __restrict__ Bl,
        const float* __restrict__ bias,
        float* __restrict__ C, ushort* __restrict__ Ch, ushort* __restrict__ Cl,
        int M, int N, int Kd)
{
    int brow, bcol;
    swz_block(brow, bcol, 128);
    gemm_body<RELU, OMODE>(Ah, Al, Bh, Bl, bias, C, Ch, Cl, M, N, Kd, brow, bcol);
}

// q/k/v projections fused into one dispatch (grid.z = 3 -> 768 blocks)
struct QkvArgs {
    const ushort* Ah[3]; const ushort* Al[3];
    const ushort* Bh[3]; const ushort* Bl[3];
    const float*  bias[3];
    ushort*       Co[3];
};

__global__ __launch_bounds__(256) void gemm_qkv(QkvArgs qa, int M, int N, int Kd)
{
    int brow, bcol;
    swz_block(brow, bcol, 128);
    const int z = blockIdx.z;
    gemm_body<false, 2>(qa.Ah[z], qa.Al[z], qa.Bh[z], qa.Bl[z], qa.bias[z],
                        nullptr, qa.Co[z], nullptr, M, N, Kd, brow, bcol);
}

// ---------------------------------------------------------------------------
// FFN1: 256^2 tile, BK=32, 8 waves (512 thr), 3 term-phases per K-tile
// (hh, hl, lh) with counted vmcnt + raw s_barrier (T3+T4). Split planes in
// LDS: S[2 bufs][4 planes: Ah,Al,Bh,Bl][256*32]. Plane-arrival order per
// staged batch: [Ah,Bh | Bl | Al]; phase p's ds_reads are confirmed by
// phase p-1's vmcnt+barrier. Epilogue: bias + ReLU + split-plane C write.
// ---------------------------------------------------------------------------
__global__ __launch_bounds__(512, 2) void gemm_ffn1_8p(
        const ushort* __restrict__ Ah, const ushort* __restrict__ Al,
        const ushort* __restrict__ Bh, const ushort* __restrict__ Bl,
        const float* __restrict__ bias,
        ushort* __restrict__ Ch, ushort* __restrict__ Cl,
        int M, int N, int Kd)
{
    __shared__ __align__(16) ushort S[2][4][256 * 32];   // 128KB

    const int t    = threadIdx.x;
    const int lane = t & 63;
    const int w    = t >> 6;
    const int wrofs = (w >> 2) * 128;    // 2 M-halves
    const int wcofs = (w & 3) * 64;      // 4 N-quarters

    int brow, bcol;
    {
        const int nx  = gridDim.x;
        const int lin = blockIdx.y * nx + blockIdx.x;
        const int cpx = (nx * gridDim.y) >> 3;
        const int swz = (lin & 7) * cpx + (lin >> 3);
        brow = (swz / nx) * 256;
        bcol = (swz % nx) * 256;
    }

    const int fr = lane & 15;
    const int g  = lane >> 4;
    const int sS = ((g ^ ((fr >> 1) & 3)) << 3);

    // staging: wave w stages chunks {2w, 2w+1} of every plane (1KB each).
    // chunk c covers rows [16c,16c+16); lane l -> row 16c+(l>>2), swz slot.
    const int c0    = w * 2;
    const int lrow  = lane >> 2;
    const int lslot = ((lane & 3) ^ ((lane >> 3) & 3)) << 3;

    f32x4_t acc[8][4];
    #pragma unroll
    for (int i = 0; i < 8; ++i)
        #pragma unroll
        for (int j = 0; j < 4; ++j)
            acc[i][j] = (f32x4_t){0.f, 0.f, 0.f, 0.f};

    // stage one plane (2 chunks for this wave) of tile at k0 into buf
    auto stage = [&](const ushort* gp, int rb, int pl, int buf, int k0) {
        #pragma unroll
        for (int i = 0; i < 2; ++i) {
            int c = c0 + i;
            gl_lds16(gp + (size_t)(rb + c * 16 + lrow) * Kd + k0 + lslot,
                     &S[buf][pl][c * 512]);
        }
    };

    const int NT = Kd >> 5;   // 32 K-tiles for K=1024

    // prologue: batch 0 in issue order [Ah,Bh,Bl,Al]; confirm Ah,Bh.
    stage(Ah, brow, 0, 0, 0);
    stage(Bh, bcol, 2, 0, 0);
    stage(Bl, bcol, 3, 0, 0);
    stage(Al, brow, 1, 0, 0);
    asm volatile("s_waitcnt vmcnt(4)" ::: "memory");
    __builtin_amdgcn_s_barrier();

    for (int tt = 0; tt < NT; ++tt) {
        const int cur = tt & 1, nxt = cur ^ 1;
        const int kn  = (tt + 1) << 5;
        const bool more = (tt + 1 < NT);

        // ---- phase 0: hh.  reads Ah,Bh(t); stages Ah,Bh(t+1).
        if (more) { stage(Ah, brow, 0, nxt, kn); stage(Bh, bcol, 2, nxt, kn); }
        bf16x8_t ahf[8], bhf[4];
        #pragma unroll
        for (int i = 0; i < 8; ++i)
            ahf[i] = *(const bf16x8_t*)&S[cur][0][(wrofs + i * 16 + fr) * 32 + sS];
        #pragma unroll
        for (int j = 0; j < 4; ++j)
            bhf[j] = *(const bf16x8_t*)&S[cur][2][(wcofs + j * 16 + fr) * 32 + sS];
        if (more) asm volatile("s_waitcnt vmcnt(6)" ::: "memory");   // Bl(t) done
        else      asm volatile("s_waitcnt vmcnt(2)" ::: "memory");
        __builtin_amdgcn_s_barrier();
        __builtin_amdgcn_sched_barrier(0);
        __builtin_amdgcn_s_setprio(1);
        #pragma unroll
        for (int i = 0; i < 8; ++i)
            #pragma unroll
            for (int j = 0; j < 4; ++j)
                acc[i][j] = __builtin_amdgcn_mfma_f32_16x16x32_bf16(ahf[i], bhf[j], acc[i][j], 0, 0, 0);
        __builtin_amdgcn_s_setprio(0);

        // ---- phase 1: hl.  reads Bl(t); stages Bl(t+1).  (ahf held)
        if (more) stage(Bl, bcol, 3, nxt, kn);
        bf16x8_t blf[4];
        #pragma unroll
        for (int j = 0; j < 4; ++j)
            blf[j] = *(const bf16x8_t*)&S[cur][3][(wcofs + j * 16 + fr) * 32 + sS];
        if (more) asm volatile("s_waitcnt vmcnt(6)" ::: "memory");   // Al(t) done
        else      asm volatile("s_waitcnt vmcnt(0)" ::: "memory");
        __builtin_amdgcn_s_barrier();
        __builtin_amdgcn_sched_barrier(0);
        __builtin_amdgcn_s_setprio(1);
        #pragma unroll
        for (int i = 0; i < 8; ++i)
            #pragma unroll
            for (int j = 0; j < 4; ++j)
                acc[i][j] = __builtin_amdgcn_mfma_f32_16x16x32_bf16(ahf[i], blf[j], acc[i][j], 0, 0, 0);
        __builtin_amdgcn_s_setprio(0);

        // ---- phase 2: lh.  reads Al(t); stages Al(t+1).  (bhf held)
        if (more) stage(Al, brow, 1, nxt, kn);
        bf16x8_t alf[8];
        #pragma unroll
        for (int i = 0; i < 8; ++i)
            alf[i] = *(const bf16x8_t*)&S[cur][1][(wrofs + i * 16 + fr) * 32 + sS];
        if (more) asm volatile("s_waitcnt vmcnt(4)" ::: "memory");   // Ah,Bh(t+1) done
        else      asm volatile("s_waitcnt vmcnt(0)" ::: "memory");
        __builtin_amdgcn_s_barrier();
        __builtin_amdgcn_sched_barrier(0);
        __builtin_amdgcn_s_setprio(1);
        #pragma unroll
        for (int i = 0; i < 8; ++i)
            #pragma unroll
            for (int j = 0; j < 4; ++j)
                acc[i][j] = __builtin_amdgcn_mfma_f32_16x16x32_bf16(alf[i], bhf[j], acc[i][j], 0, 0, 0);
        __builtin_amdgcn_s_setprio(0);
    }

    // epilogue: bias + ReLU + split-plane write
    const int cl = lane & 15;
    const int rq = (lane >> 4) * 4;
    #pragma unroll
    for (int j = 0; j < 4; ++j) {
        int col = bcol + wcofs + j * 16 + cl;
        float bv = bias[col];
        #pragma unroll
        for (int i = 0; i < 8; ++i) {
            #pragma unroll
            for (int r = 0; r < 4; ++r) {
                int row = brow + wrofs + i * 16 + rq + r;
                float v = fmaxf(acc[i][j][r] + bv, 0.f);
                ushort h = f2bf_rne(v);
                Ch[(size_t)row * N + col] = h;
                Cl[(size_t)row * N + col] = f2bf_rne(v - bf2f(h));
            }
        }
    }
}

// ---------------------------------------------------------------------------
// MFMA flash attention (validated round 4). 1024 blocks, 4 waves, QBLK=64,
// KVBLK=32; online softmax via 16-lane shfl_xor; output split planes.
// ---------------------------------------------------------------------------
__global__ __launch_bounds__(256) void flash_attn_mfma(
        const ushort* __restrict__ qh, const ushort* __restrict__ kh,
        const ushort* __restrict__ vh,
        ushort* __restrict__ Oh, ushort* __restrict__ Ol)
{
    __shared__ __align__(16) ushort sk[32 * 72];
    __shared__ __align__(16) ushort svt[64 * 40];
    __shared__ __align__(16) ushort pbuf[4][16 * 40];

    const int bid  = blockIdx.x;
    const int slot = bid >> 3;
    const int bh   = (bid & 7) * 8 + (slot >> 4);
    const int qt   = slot & 15;
    const int b    = bh >> 4;
    const int h    = bh & 15;
    const int qb   = qt * 64;

    const int t = threadIdx.x, lane = t & 63, w = t >> 6;
    const int l15 = lane & 15, g = lane >> 4;

    bf16x8_t qf[2];
    {
        size_t qrow = ((size_t)(b * NQ_) + qb + w * 16 + l15) * D_ + h * DH_;
        qf[0] = *(const bf16x8_t*)&qh[qrow + 0  + 8 * g];
        qf[1] = *(const bf16x8_t*)&qh[qrow + 32 + 8 * g];
    }

    f32x4_t acc[4];
    #pragma unroll
    for (int dt = 0; dt < 4; ++dt) acc[dt] = (f32x4_t){0.f, 0.f, 0.f, 0.f};
    float m[4]    = {-INFINITY, -INFINITY, -INFINITY, -INFINITY};
    float lsum[4] = {0.f, 0.f, 0.f, 0.f};

    const int kkv = t >> 3,  kds = (t & 7) * 8;
    const int vkv = t & 31,  vds = (t >> 5) * 8;
    const size_t kvbase = (size_t)(b * NK_) * D_ + h * DH_;

    for (int kt = 0; kt < NK_; kt += 32) {
        __syncthreads();
        {
            bf16x8_t kk = *(const bf16x8_t*)&kh[kvbase + (size_t)(kt + kkv) * D_ + kds];
            *(bf16x8_t*)&sk[kkv * 72 + kds] = kk;
            bf16x8_t vv = *(const bf16x8_t*)&vh[kvbase + (size_t)(kt + vkv) * D_ + vds];
            #pragma unroll
            for (int j = 0; j < 8; ++j)
                svt[(vds + j) * 40 + vkv] = (ushort)vv[j];
        }
        __syncthreads();

        f32x4_t s0 = (f32x4_t){0.f,0.f,0.f,0.f};
        f32x4_t s1 = (f32x4_t){0.f,0.f,0.f,0.f};
        #pragma unroll
        for (int c = 0; c < 2; ++c) {
            bf16x8_t k0 = *(const bf16x8_t*)&sk[(l15     ) * 72 + 32 * c + 8 * g];
            bf16x8_t k1 = *(const bf16x8_t*)&sk[(l15 + 16) * 72 + 32 * c + 8 * g];
            s0 = __builtin_amdgcn_mfma_f32_16x16x32_bf16(qf[c], k0, s0, 0, 0, 0);
            s1 = __builtin_amdgcn_mfma_f32_16x16x32_bf16(qf[c], k1, s1, 0, 0, 0);
        }

        float p0[4], p1[4], corr[4];
        #pragma unroll
        for (int r = 0; r < 4; ++r) {
            float e0 = s0[r] * SCALE_, e1 = s1[r] * SCALE_;
            float tm = fmaxf(e0, e1);
            tm = fmaxf(tm, __shfl_xor(tm, 1, 64));
            tm = fmaxf(tm, __shfl_xor(tm, 2, 64));
            tm = fmaxf(tm, __shfl_xor(tm, 4, 64));
            tm = fmaxf(tm, __shfl_xor(tm, 8, 64));
            float mn = fmaxf(m[r], tm);
            corr[r] = __expf(m[r] - mn);
            p0[r] = __expf(e0 - mn);
            p1[r] = __expf(e1 - mn);
            float ps = p0[r] + p1[r];
            ps += __shfl_xor(ps, 1, 64);
            ps += __shfl_xor(ps, 2, 64);
            ps += __shfl_xor(ps, 4, 64);
            ps += __shfl_xor(ps, 8, 64);
            lsum[r] = lsum[r] * corr[r] + ps;
            m[r] = mn;
        }
        #pragma unroll
        for (int dt = 0; dt < 4; ++dt)
            #pragma unroll
            for (int r = 0; r < 4; ++r)
                acc[dt][r] *= corr[r];

        ushort* pw = &pbuf[w][0];
        #pragma unroll
        for (int r = 0; r < 4; ++r) {
            pw[(4 * g + r) * 40 + l15     ] = f2bf_rne(p0[r]);
            pw[(4 * g + r) * 40 + l15 + 16] = f2bf_rne(p1[r]);
        }
        bf16x8_t pa = *(const bf16x8_t*)&pw[l15 * 40 + 8 * g];

        #pragma unroll
        for (int dt = 0; dt < 4; ++dt) {
            bf16x8_t vf = *(const bf16x8_t*)&svt[(16 * dt + l15) * 40 + 8 * g];
            acc[dt] = __builtin_amdgcn_mfma_f32_16x16x32_bf16(pa, vf, acc[dt], 0, 0, 0);
        }
    }

    float inv[4];
    #pragma unroll
    for (int r = 0; r < 4; ++r) inv[r] = 1.0f / lsum[r];
    #pragma unroll
    for (int dt = 0; dt < 4; ++dt) {
        #pragma unroll
        for (int r = 0; r < 4; ++r) {
            int row = b * NQ_ + qb + w * 16 + 4 * g + r;
            int col = h * DH_ + 16 * dt + l15;
            float v = acc[dt][r] * inv[r];
            ushort hh = f2bf_rne(v);
            Oh[(size_t)row * D_ + col] = hh;
            Ol[(size_t)row * D_ + col] = f2bf_rne(v - bf2f(hh));
        }
    }
}

// ---------------------------------------------------------------------------
// out = LayerNorm(a + r) * g + be. SPLIT: also emit bf16 hi/lo planes.
// ---------------------------------------------------------------------------
template<bool SPLIT>
__global__ __launch_bounds__(256) void add_ln(const float* __restrict__ a,
        const float* __restrict__ r, const float* __restrict__ g,
        const float* __restrict__ be, float* __restrict__ out,
        ushort* __restrict__ oh, ushort* __restrict__ ol)
{
    const int row = blockIdx.x;
    const int t = threadIdx.x;
    float vals[4];
    float s1 = 0.0f, s2 = 0.0f;
    #pragma unroll
    for (int i = 0; i < 4; ++i) {
        int col = t + i * 256;
        float vv = a[(size_t)row * D_ + col] + r[(size_t)row * D_ + col];
        vals[i] = vv;
        s1 += vv;
        s2 += vv * vv;
    }
    #pragma unroll
    for (int off = 32; off > 0; off >>= 1) {
        s1 += __shfl_down(s1, off, 64);
        s2 += __shfl_down(s2, off, 64);
    }
    __shared__ float p1[4], p2[4];
    const int wave = t >> 6;
    if ((t & 63) == 0) { p1[wave] = s1; p2[wave] = s2; }
    __syncthreads();
    s1 = p1[0] + p1[1] + p1[2] + p1[3];
    s2 = p2[0] + p2[1] + p2[2] + p2[3];
    const float mean = s1 * (1.0f / D_);
    const float var  = s2 * (1.0f / D_) - mean * mean;
    const float rstd = rsqrtf(var + LN_EPS_);
    #pragma unroll
    for (int i = 0; i < 4; ++i) {
        int col = t + i * 256;
        float v = (vals[i] - mean) * rstd * g[col] + be[col];
        out[(size_t)row * D_ + col] = v;
        if (SPLIT) {
            ushort h = f2bf_rne(v);
            oh[(size_t)row * D_ + col] = h;
            ol[(size_t)row * D_ + col] = f2bf_rne(v - bf2f(h));
        }
    }
}

// ---------------------------------------------------------------------------
extern "C" void kernel_launch(void* const* d_in, const int* in_sizes, int n_in,
                              void* d_out, int out_size, void* d_ws, size_t ws_size,
                              hipStream_t stream)
{
    const float* Q   = (const float*)d_in[0];
    const float* K   = (const float*)d_in[1];
    const float* Wq  = (const float*)d_in[2];
    const float* bq  = (const float*)d_in[3];
    const float* Wk  = (const float*)d_in[4];
    const float* bk  = (const float*)d_in[5];
    const float* Wv  = (const float*)d_in[6];
    const float* bv  = (const float*)d_in[7];
    const float* Wo  = (const float*)d_in[8];
    const float* bo  = (const float*)d_in[9];
    const float* W1  = (const float*)d_in[10];
    const float* b1  = (const float*)d_in[11];
    const float* W2  = (const float*)d_in[12];
    const float* b2  = (const float*)d_in[13];
    const float* g0  = (const float*)d_in[14];
    const float* be0 = (const float*)d_in[15];
    const float* g1  = (const float*)d_in[16];
    const float* be1 = (const float*)d_in[17];

    unsigned char* Wb = (unsigned char*)d_ws;
    const size_t MBy = 1ull << 20;

    ushort* Qh  = (ushort*)(Wb +  0 * MBy);
    ushort* Ql  = (ushort*)(Wb +  8 * MBy);
    ushort* Kh  = (ushort*)(Wb + 16 * MBy);
    ushort* Kl  = (ushort*)(Wb + 24 * MBy);
    ushort* Wqh = (ushort*)(Wb + 32 * MBy);
    ushort* Wql = (ushort*)(Wb + 34 * MBy);
    ushort* Wkh = (ushort*)(Wb + 36 * MBy);
    ushort* Wkl = (ushort*)(Wb + 38 * MBy);
    ushort* Wvh = (ushort*)(Wb + 40 * MBy);
    ushort* Wvl = (ushort*)(Wb + 42 * MBy);
    ushort* Woh = (ushort*)(Wb + 44 * MBy);
    ushort* Wol = (ushort*)(Wb + 46 * MBy);
    ushort* qhp = (ushort*)(Wb + 48 * MBy);
    ushort* khp = (ushort*)(Wb + 56 * MBy);
    ushort* vhp = (ushort*)(Wb + 64 * MBy);
    ushort* aOh = (ushort*)(Wb + 72 * MBy);
    ushort* aOl = (ushort*)(Wb + 80 * MBy);

    float*  oprj = (float*)(Wb + 16 * MBy);
    float*  Xf   = (float*)(Wb +  0 * MBy);
    ushort* Xh   = (ushort*)(Wb + 48 * MBy);
    ushort* Xl   = (ushort*)(Wb + 56 * MBy);
    ushort* W1h  = (ushort*)(Wb + 64 * MBy);
    ushort* W1l  = (ushort*)(Wb + 72 * MBy);
    ushort* Hih  = (ushort*)(Wb + 80 * MBy);   // 32MB
    ushort* Hil  = (ushort*)(Wb + 16 * MBy);   // 32MB
    ushort* W2h  = (ushort*)(Wb + 48 * MBy);
    ushort* W2l  = (ushort*)(Wb + 56 * MBy);
    float*  Y    = (float*)(Wb + 64 * MBy);

    const int M = B_ * NQ_;
    const int n4act = M * D_ / 4;
    dim3 blk(256);
    dim3 gD(D_ / 128, M / 128);
    dim3 gQKV(D_ / 128, M / 128, 3);

    split_rows<<<n4act / 256, blk, 0, stream>>>(Q, Qh, Ql, n4act);
    split_rows<<<n4act / 256, blk, 0, stream>>>(K, Kh, Kl, n4act);
    split_tr<<<dim3(D_/32, D_/32), blk, 0, stream>>>(Wq, Wqh, Wql, D_, D_);
    split_tr<<<dim3(D_/32, D_/32), blk, 0, stream>>>(Wk, Wkh, Wkl, D_, D_);
    split_tr<<<dim3(D_/32, D_/32), blk, 0, stream>>>(Wv, Wvh, Wvl, D_, D_);
    split_tr<<<dim3(D_/32, D_/32), blk, 0, stream>>>(Wo, Woh, Wol, D_, D_);

    QkvArgs qa;
    qa.Ah[0] = Qh;  qa.Al[0] = Ql;  qa.Bh[0] = Wqh; qa.Bl[0] = Wql; qa.bias[0] = bq; qa.Co[0] = qhp;
    qa.Ah[1] = Kh;  qa.Al[1] = Kl;  qa.Bh[1] = Wkh; qa.Bl[1] = Wkl; qa.bias[1] = bk; qa.Co[1] = khp;
    qa.Ah[2] = Kh;  qa.Al[2] = Kl;  qa.Bh[2] = Wvh; qa.Bl[2] = Wvl; qa.bias[2] = bv; qa.Co[2] = vhp;
    gemm_qkv<<<gQKV, blk, 0, stream>>>(qa, M, D_, D_);

    flash_attn_mfma<<<dim3(1024), blk, 0, stream>>>(qhp, khp, vhp, aOh, aOl);

    gemm_mfma<false,0><<<gD, blk, 0, stream>>>(aOh, aOl, Woh, Wol, bo, oprj, nullptr, nullptr, M, D_, D_);
    add_ln<true><<<M, blk, 0, stream>>>(oprj, Q, g0, be0, Xf, Xh, Xl);

    split_tr<<<dim3(DFF_/32, D_/32), blk, 0, stream>>>(W1, W1h, W1l, D_, DFF_);
    gemm_ffn1_8p<<<dim3(DFF_/256, M/256), dim3(512), 0, stream>>>(
        Xh, Xl, W1h, W1l, b1, Hih, Hil, M, DFF_, D_);
    split_tr<<<dim3(D_/32, DFF_/32), blk, 0, stream>>>(W2, W2h, W2l, DFF_, D_);
    gemm_mfma<false,0><<<gD, blk, 0, stream>>>(Hih, Hil, W2h, W2l, b2, Y, nullptr, nullptr, M, D_, DFF_);
    add_ln<false><<<M, blk, 0, stream>>>(Y, Xf, g1, be1, (float*)d_out, nullptr, nullptr);
}

// Round 9
// 486.805 us; speedup vs baseline: 1.1370x; 1.1370x over previous
//
#include <hip/hip_runtime.h>
#include <math.h>

#define B_   4
#define NQ_  1024
#define NK_  1024
#define D_   1024
#define H_   16
#define DH_  64
#define DFF_ 4096
#define SCALE_ (1.0f/32.0f)   // 1/sqrt(D)
#define LN_EPS_ 1e-5f

typedef __attribute__((ext_vector_type(8))) short bf16x8_t;  // 8 bf16 = 4 VGPR
typedef __attribute__((ext_vector_type(4))) float f32x4_t;

__device__ __forceinline__ ushort f2bf_rne(float x) {
    unsigned u = __float_as_uint(x);
    unsigned r = (u + 0x7FFFu + ((u >> 16) & 1u)) >> 16;
    return (ushort)r;
}
__device__ __forceinline__ float bf2f(ushort h) {
    return __uint_as_float(((unsigned)h) << 16);
}

// async global->LDS, 16B per lane. LDS dest = wave-uniform base + lane*16.
__device__ __forceinline__ void gl_lds16(const ushort* g, ushort* l) {
    __builtin_amdgcn_global_load_lds(
        (const __attribute__((address_space(1))) unsigned int*)g,
        (__attribute__((address_space(3))) unsigned int*)l, 16, 0, 0);
}

// ---------------------------------------------------------------------------
// fp32 -> (hi,lo) bf16 planes.
// ---------------------------------------------------------------------------
__global__ __launch_bounds__(256) void split_rows(const float* __restrict__ src,
        ushort* __restrict__ hi, ushort* __restrict__ lo, int n4)
{
    int i = blockIdx.x * 256 + threadIdx.x;
    if (i >= n4) return;
    float4 v = ((const float4*)src)[i];
    ushort4 h, l;
    h.x = f2bf_rne(v.x); l.x = f2bf_rne(v.x - bf2f(h.x));
    h.y = f2bf_rne(v.y); l.y = f2bf_rne(v.y - bf2f(h.y));
    h.z = f2bf_rne(v.z); l.z = f2bf_rne(v.z - bf2f(h.z));
    h.w = f2bf_rne(v.w); l.w = f2bf_rne(v.w - bf2f(h.w));
    ((ushort4*)hi)[i] = h;
    ((ushort4*)lo)[i] = l;
}

// ---------------------------------------------------------------------------
// Weight split + transpose: W[K][N] fp32 -> planes Wt[N][K] bf16.
// ---------------------------------------------------------------------------
__global__ __launch_bounds__(256) void split_tr(const float* __restrict__ Wsrc,
        ushort* __restrict__ th, ushort* __restrict__ tl, int K, int N)
{
    __shared__ float tile[32][33];
    const int nb = blockIdx.x * 32, kb = blockIdx.y * 32;
    const int t = threadIdx.x;
    {
        int r = t >> 3, c4 = (t & 7) * 4;
        float4 v = *(const float4*)&Wsrc[(size_t)(kb + r) * N + nb + c4];
        tile[r][c4 + 0] = v.x; tile[r][c4 + 1] = v.y;
        tile[r][c4 + 2] = v.z; tile[r][c4 + 3] = v.w;
    }
    __syncthreads();
    {
        int n = t >> 3, k4 = (t & 7) * 4;
        float a0 = tile[k4 + 0][n], a1 = tile[k4 + 1][n];
        float a2 = tile[k4 + 2][n], a3 = tile[k4 + 3][n];
        ushort4 h, l;
        h.x = f2bf_rne(a0); l.x = f2bf_rne(a0 - bf2f(h.x));
        h.y = f2bf_rne(a1); l.y = f2bf_rne(a1 - bf2f(h.y));
        h.z = f2bf_rne(a2); l.z = f2bf_rne(a2 - bf2f(h.z));
        h.w = f2bf_rne(a3); l.w = f2bf_rne(a3 - bf2f(h.w));
        size_t o = (size_t)(nb + n) * K + kb + k4;
        *(ushort4*)&th[o] = h;
        *(ushort4*)&tl[o] = l;
    }
}

// ---------------------------------------------------------------------------
// 2-phase dbuf MFMA GEMM (K-loop validated r7). 128^2 tile, 4 waves.
// OMODE: 0 = fp32 out, 1 = split planes out, 2 = hi-only bf16 out.
// NEW (r9): coalesced epilogue for OMODE 1/2 — per-wave 64x64 f32 LDS bounce
// (re-uses staging LDS after final K-loop barrier), then 16B/lane row stores.
// Fixes 3.4x HBM write amplification seen in r8 (WRITE_SIZE 219MB vs 64MB).
// ---------------------------------------------------------------------------
template<bool RELU, int OMODE>
__device__ __forceinline__ void gemm_body(
        const ushort* __restrict__ Ah, const ushort* __restrict__ Al,
        const ushort* __restrict__ Bh, const ushort* __restrict__ Bl,
        const float* __restrict__ bias,
        float* __restrict__ C, ushort* __restrict__ Ch, ushort* __restrict__ Cl,
        int M, int N, int Kd, int brow, int bcol)
{
    __shared__ __align__(16) ushort sAll[2][4][128 * 32];   // 64KB dbuf

    const int t    = threadIdx.x;
    const int lane = t & 63;
    const int w    = t >> 6;
    const int wr   = (w >> 1) * 64;
    const int wc   = (w & 1) * 64;

    f32x4_t acc[4][4];
    #pragma unroll
    for (int i = 0; i < 4; ++i)
        #pragma unroll
        for (int j = 0; j < 4; ++j)
            acc[i][j] = (f32x4_t){0.f, 0.f, 0.f, 0.f};

    const int fr = lane & 15;
    const int g  = lane >> 4;
    const int sS = ((g ^ ((fr >> 1) & 3)) << 3);

    const ushort* gplane = (w == 0) ? Ah : (w == 1) ? Al : (w == 2) ? Bh : Bl;
    const int     rb     = (w < 2) ? brow : bcol;
    const size_t  grow   = (size_t)(rb + (lane >> 2)) * Kd
                         + (((lane & 3) ^ ((lane >> 3) & 3)) << 3);

    {
        ushort* lp = &sAll[0][w][0];
        #pragma unroll
        for (int i = 0; i < 8; ++i)
            gl_lds16(gplane + grow + (size_t)(16 * i) * Kd, lp + i * 512);
    }
    __syncthreads();

    int cur = 0;
    for (int k0 = 0; k0 < Kd; k0 += 32) {
        if (k0 + 32 < Kd) {
            ushort* lp = &sAll[cur ^ 1][w][0];
            #pragma unroll
            for (int i = 0; i < 8; ++i)
                gl_lds16(gplane + grow + (size_t)(16 * i) * Kd + k0 + 32, lp + i * 512);
        }
        __builtin_amdgcn_sched_barrier(0);

        bf16x8_t ah[4], al[4], bh[4], bl[4];
        #pragma unroll
        for (int i = 0; i < 4; ++i) {
            int m = wr + i * 16 + fr;
            ah[i] = *(const bf16x8_t*)&sAll[cur][0][m * 32 + sS];
            al[i] = *(const bf16x8_t*)&sAll[cur][1][m * 32 + sS];
        }
        #pragma unroll
        for (int j = 0; j < 4; ++j) {
            int n = wc + j * 16 + fr;
            bh[j] = *(const bf16x8_t*)&sAll[cur][2][n * 32 + sS];
            bl[j] = *(const bf16x8_t*)&sAll[cur][3][n * 32 + sS];
        }
        #pragma unroll
        for (int i = 0; i < 4; ++i)
            #pragma unroll
            for (int j = 0; j < 4; ++j) {
                acc[i][j] = __builtin_amdgcn_mfma_f32_16x16x32_bf16(ah[i], bh[j], acc[i][j], 0, 0, 0);
                acc[i][j] = __builtin_amdgcn_mfma_f32_16x16x32_bf16(ah[i], bl[j], acc[i][j], 0, 0, 0);
                acc[i][j] = __builtin_amdgcn_mfma_f32_16x16x32_bf16(al[i], bh[j], acc[i][j], 0, 0, 0);
            }

        __syncthreads();   // readers done + prefetch drained (also guards epi reuse)
        cur ^= 1;
    }

    const int cl = lane & 15;
    const int rq = (lane >> 4) * 4;

    if (OMODE == 0) {
        #pragma unroll
        for (int j = 0; j < 4; ++j) {
            int col = bcol + wc + j * 16 + cl;
            float bv = bias[col];
            #pragma unroll
            for (int i = 0; i < 4; ++i)
                #pragma unroll
                for (int r = 0; r < 4; ++r) {
                    int row = brow + wr + i * 16 + rq + r;
                    float v = acc[i][j][r] + bv;
                    if (RELU) v = fmaxf(v, 0.f);
                    C[(size_t)row * N + col] = v;
                }
        }
    } else {
        // coalesced bounce: wave-private 64x64 f32 view over staging LDS
        float* E = (float*)&sAll[0][0][0] + w * 4096;   // 16KB per wave
        #pragma unroll
        for (int j = 0; j < 4; ++j) {
            float bv = bias[bcol + wc + j * 16 + cl];
            #pragma unroll
            for (int i = 0; i < 4; ++i)
                #pragma unroll
                for (int r = 0; r < 4; ++r) {
                    float v = acc[i][j][r] + bv;
                    if (RELU) v = fmaxf(v, 0.f);
                    E[(i * 16 + rq + r) * 64 + j * 16 + cl] = v;
                }
        }
        __syncthreads();
        const int rr8 = lane >> 3;          // 0..7
        const int c8  = (lane & 7) * 8;     // col base (8 f32 = 32B aligned)
        #pragma unroll
        for (int p = 0; p < 8; ++p) {
            int rl = p * 8 + rr8;
            float4 va = *(float4*)&E[rl * 64 + c8];
            float4 vb = *(float4*)&E[rl * 64 + c8 + 4];
            float v[8] = {va.x, va.y, va.z, va.w, vb.x, vb.y, vb.z, vb.w};
            bf16x8_t hv, lv;
            #pragma unroll
            for (int q = 0; q < 8; ++q) {
                ushort hh = f2bf_rne(v[q]);
                hv[q] = (short)hh;
                lv[q] = (short)f2bf_rne(v[q] - bf2f(hh));
            }
            size_t o = (size_t)(brow + wr + rl) * N + (bcol + wc + c8);
            *(bf16x8_t*)&Ch[o] = hv;
            if (OMODE == 1) *(bf16x8_t*)&Cl[o] = lv;
        }
    }
}

// bijective XCD-chunked swizzle (nwg % 8 == 0 for all our grids)
__device__ __forceinline__ void swz_block(int& brow, int& bcol, int tile) {
    const int nx  = gridDim.x;
    const int lin = blockIdx.y * nx + blockIdx.x;
    const int cpx = (nx * gridDim.y) >> 3;
    const int swz = (lin & 7) * cpx + (lin >> 3);
    brow = (swz / nx) * tile;
    bcol = (swz % nx) * tile;
}

template<bool RELU, int OMODE>
__global__ __launch_bounds__(256) void gemm_mfma(
        const ushort* __restrict__ Ah, const ushort* __restrict__ Al,
        const ushort* __restrict__ Bh, const ushort* __restrict__ Bl,
        const float* __restrict__ bias,
        float* __restrict__ C, ushort* __restrict__ Ch, ushort* __restrict__ Cl,
        int M, int N, int Kd)
{
    int brow, bcol;
    swz_block(brow, bcol, 128);
    gemm_body<RELU, OMODE>(Ah, Al, Bh, Bl, bias, C, Ch, Cl, M, N, Kd, brow, bcol);
}

// q/k/v projections fused into one dispatch (grid.z = 3 -> 768 blocks)
struct QkvArgs {
    const ushort* Ah[3]; const ushort* Al[3];
    const ushort* Bh[3]; const ushort* Bl[3];
    const float*  bias[3];
    ushort*       Co[3];
};

__global__ __launch_bounds__(256) void gemm_qkv(QkvArgs qa, int M, int N, int Kd)
{
    int brow, bcol;
    swz_block(brow, bcol, 128);
    const int z = blockIdx.z;
    gemm_body<false, 2>(qa.Ah[z], qa.Al[z], qa.Bh[z], qa.Bl[z], qa.bias[z],
                        nullptr, qa.Co[z], nullptr, M, N, Kd, brow, bcol);
}

// ---------------------------------------------------------------------------
// MFMA flash attention (validated round 4). 1024 blocks, 4 waves, QBLK=64,
// KVBLK=32; online softmax via 16-lane shfl_xor; output split planes.
// ---------------------------------------------------------------------------
__global__ __launch_bounds__(256) void flash_attn_mfma(
        const ushort* __restrict__ qh, const ushort* __restrict__ kh,
        const ushort* __restrict__ vh,
        ushort* __restrict__ Oh, ushort* __restrict__ Ol)
{
    __shared__ __align__(16) ushort sk[32 * 72];
    __shared__ __align__(16) ushort svt[64 * 40];
    __shared__ __align__(16) ushort pbuf[4][16 * 40];

    const int bid  = blockIdx.x;
    const int slot = bid >> 3;
    const int bh   = (bid & 7) * 8 + (slot >> 4);
    const int qt   = slot & 15;
    const int b    = bh >> 4;
    const int h    = bh & 15;
    const int qb   = qt * 64;

    const int t = threadIdx.x, lane = t & 63, w = t >> 6;
    const int l15 = lane & 15, g = lane >> 4;

    bf16x8_t qf[2];
    {
        size_t qrow = ((size_t)(b * NQ_) + qb + w * 16 + l15) * D_ + h * DH_;
        qf[0] = *(const bf16x8_t*)&qh[qrow + 0  + 8 * g];
        qf[1] = *(const bf16x8_t*)&qh[qrow + 32 + 8 * g];
    }

    f32x4_t acc[4];
    #pragma unroll
    for (int dt = 0; dt < 4; ++dt) acc[dt] = (f32x4_t){0.f, 0.f, 0.f, 0.f};
    float m[4]    = {-INFINITY, -INFINITY, -INFINITY, -INFINITY};
    float lsum[4] = {0.f, 0.f, 0.f, 0.f};

    const int kkv = t >> 3,  kds = (t & 7) * 8;
    const int vkv = t & 31,  vds = (t >> 5) * 8;
    const size_t kvbase = (size_t)(b * NK_) * D_ + h * DH_;

    for (int kt = 0; kt < NK_; kt += 32) {
        __syncthreads();
        {
            bf16x8_t kk = *(const bf16x8_t*)&kh[kvbase + (size_t)(kt + kkv) * D_ + kds];
            *(bf16x8_t*)&sk[kkv * 72 + kds] = kk;
            bf16x8_t vv = *(const bf16x8_t*)&vh[kvbase + (size_t)(kt + vkv) * D_ + vds];
            #pragma unroll
            for (int j = 0; j < 8; ++j)
                svt[(vds + j) * 40 + vkv] = (ushort)vv[j];
        }
        __syncthreads();

        f32x4_t s0 = (f32x4_t){0.f,0.f,0.f,0.f};
        f32x4_t s1 = (f32x4_t){0.f,0.f,0.f,0.f};
        #pragma unroll
        for (int c = 0; c < 2; ++c) {
            bf16x8_t k0 = *(const bf16x8_t*)&sk[(l15     ) * 72 + 32 * c + 8 * g];
            bf16x8_t k1 = *(const bf16x8_t*)&sk[(l15 + 16) * 72 + 32 * c + 8 * g];
            s0 = __builtin_amdgcn_mfma_f32_16x16x32_bf16(qf[c], k0, s0, 0, 0, 0);
            s1 = __builtin_amdgcn_mfma_f32_16x16x32_bf16(qf[c], k1, s1, 0, 0, 0);
        }

        float p0[4], p1[4], corr[4];
        #pragma unroll
        for (int r = 0; r < 4; ++r) {
            float e0 = s0[r] * SCALE_, e1 = s1[r] * SCALE_;
            float tm = fmaxf(e0, e1);
            tm = fmaxf(tm, __shfl_xor(tm, 1, 64));
            tm = fmaxf(tm, __shfl_xor(tm, 2, 64));
            tm = fmaxf(tm, __shfl_xor(tm, 4, 64));
            tm = fmaxf(tm, __shfl_xor(tm, 8, 64));
            float mn = fmaxf(m[r], tm);
            corr[r] = __expf(m[r] - mn);
            p0[r] = __expf(e0 - mn);
            p1[r] = __expf(e1 - mn);
            float ps = p0[r] + p1[r];
            ps += __shfl_xor(ps, 1, 64);
            ps += __shfl_xor(ps, 2, 64);
            ps += __shfl_xor(ps, 4, 64);
            ps += __shfl_xor(ps, 8, 64);
            lsum[r] = lsum[r] * corr[r] + ps;
            m[r] = mn;
        }
        #pragma unroll
        for (int dt = 0; dt < 4; ++dt)
            #pragma unroll
            for (int r = 0; r < 4; ++r)
                acc[dt][r] *= corr[r];

        ushort* pw = &pbuf[w][0];
        #pragma unroll
        for (int r = 0; r < 4; ++r) {
            pw[(4 * g + r) * 40 + l15     ] = f2bf_rne(p0[r]);
            pw[(4 * g + r) * 40 + l15 + 16] = f2bf_rne(p1[r]);
        }
        bf16x8_t pa = *(const bf16x8_t*)&pw[l15 * 40 + 8 * g];

        #pragma unroll
        for (int dt = 0; dt < 4; ++dt) {
            bf16x8_t vf = *(const bf16x8_t*)&svt[(16 * dt + l15) * 40 + 8 * g];
            acc[dt] = __builtin_amdgcn_mfma_f32_16x16x32_bf16(pa, vf, acc[dt], 0, 0, 0);
        }
    }

    float inv[4];
    #pragma unroll
    for (int r = 0; r < 4; ++r) inv[r] = 1.0f / lsum[r];
    #pragma unroll
    for (int dt = 0; dt < 4; ++dt) {
        #pragma unroll
        for (int r = 0; r < 4; ++r) {
            int row = b * NQ_ + qb + w * 16 + 4 * g + r;
            int col = h * DH_ + 16 * dt + l15;
            float v = acc[dt][r] * inv[r];
            ushort hh = f2bf_rne(v);
            Oh[(size_t)row * D_ + col] = hh;
            Ol[(size_t)row * D_ + col] = f2bf_rne(v - bf2f(hh));
        }
    }
}

// ---------------------------------------------------------------------------
// out = LayerNorm(a + r) * g + be. SPLIT: also emit bf16 hi/lo planes.
// ---------------------------------------------------------------------------
template<bool SPLIT>
__global__ __launch_bounds__(256) void add_ln(const float* __restrict__ a,
        const float* __restrict__ r, const float* __restrict__ g,
        const float* __restrict__ be, float* __restrict__ out,
        ushort* __restrict__ oh, ushort* __restrict__ ol)
{
    const int row = blockIdx.x;
    const int t = threadIdx.x;
    float vals[4];
    float s1 = 0.0f, s2 = 0.0f;
    #pragma unroll
    for (int i = 0; i < 4; ++i) {
        int col = t + i * 256;
        float vv = a[(size_t)row * D_ + col] + r[(size_t)row * D_ + col];
        vals[i] = vv;
        s1 += vv;
        s2 += vv * vv;
    }
    #pragma unroll
    for (int off = 32; off > 0; off >>= 1) {
        s1 += __shfl_down(s1, off, 64);
        s2 += __shfl_down(s2, off, 64);
    }
    __shared__ float p1[4], p2[4];
    const int wave = t >> 6;
    if ((t & 63) == 0) { p1[wave] = s1; p2[wave] = s2; }
    __syncthreads();
    s1 = p1[0] + p1[1] + p1[2] + p1[3];
    s2 = p2[0] + p2[1] + p2[2] + p2[3];
    const float mean = s1 * (1.0f / D_);
    const float var  = s2 * (1.0f / D_) - mean * mean;
    const float rstd = rsqrtf(var + LN_EPS_);
    #pragma unroll
    for (int i = 0; i < 4; ++i) {
        int col = t + i * 256;
        float v = (vals[i] - mean) * rstd * g[col] + be[col];
        out[(size_t)row * D_ + col] = v;
        if (SPLIT) {
            ushort h = f2bf_rne(v);
            oh[(size_t)row * D_ + col] = h;
            ol[(size_t)row * D_ + col] = f2bf_rne(v - bf2f(h));
        }
    }
}

// ---------------------------------------------------------------------------
extern "C" void kernel_launch(void* const* d_in, const int* in_sizes, int n_in,
                              void* d_out, int out_size, void* d_ws, size_t ws_size,
                              hipStream_t stream)
{
    const float* Q   = (const float*)d_in[0];
    const float* K   = (const float*)d_in[1];
    const float* Wq  = (const float*)d_in[2];
    const float* bq  = (const float*)d_in[3];
    const float* Wk  = (const float*)d_in[4];
    const float* bk  = (const float*)d_in[5];
    const float* Wv  = (const float*)d_in[6];
    const float* bv  = (const float*)d_in[7];
    const float* Wo  = (const float*)d_in[8];
    const float* bo  = (const float*)d_in[9];
    const float* W1  = (const float*)d_in[10];
    const float* b1  = (const float*)d_in[11];
    const float* W2  = (const float*)d_in[12];
    const float* b2  = (const float*)d_in[13];
    const float* g0  = (const float*)d_in[14];
    const float* be0 = (const float*)d_in[15];
    const float* g1  = (const float*)d_in[16];
    const float* be1 = (const float*)d_in[17];

    unsigned char* Wb = (unsigned char*)d_ws;
    const size_t MBy = 1ull << 20;

    ushort* Qh  = (ushort*)(Wb +  0 * MBy);
    ushort* Ql  = (ushort*)(Wb +  8 * MBy);
    ushort* Kh  = (ushort*)(Wb + 16 * MBy);
    ushort* Kl  = (ushort*)(Wb + 24 * MBy);
    ushort* Wqh = (ushort*)(Wb + 32 * MBy);
    ushort* Wql = (ushort*)(Wb + 34 * MBy);
    ushort* Wkh = (ushort*)(Wb + 36 * MBy);
    ushort* Wkl = (ushort*)(Wb + 38 * MBy);
    ushort* Wvh = (ushort*)(Wb + 40 * MBy);
    ushort* Wvl = (ushort*)(Wb + 42 * MBy);
    ushort* Woh = (ushort*)(Wb + 44 * MBy);
    ushort* Wol = (ushort*)(Wb + 46 * MBy);
    ushort* qhp = (ushort*)(Wb + 48 * MBy);
    ushort* khp = (ushort*)(Wb + 56 * MBy);
    ushort* vhp = (ushort*)(Wb + 64 * MBy);
    ushort* aOh = (ushort*)(Wb + 72 * MBy);
    ushort* aOl = (ushort*)(Wb + 80 * MBy);

    float*  oprj = (float*)(Wb + 16 * MBy);
    float*  Xf   = (float*)(Wb +  0 * MBy);
    ushort* Xh   = (ushort*)(Wb + 48 * MBy);
    ushort* Xl   = (ushort*)(Wb + 56 * MBy);
    ushort* W1h  = (ushort*)(Wb + 64 * MBy);
    ushort* W1l  = (ushort*)(Wb + 72 * MBy);
    ushort* Hih  = (ushort*)(Wb + 80 * MBy);   // 32MB
    ushort* Hil  = (ushort*)(Wb + 16 * MBy);   // 32MB
    ushort* W2h  = (ushort*)(Wb + 48 * MBy);
    ushort* W2l  = (ushort*)(Wb + 56 * MBy);
    float*  Y    = (float*)(Wb + 64 * MBy);

    const int M = B_ * NQ_;
    const int n4act = M * D_ / 4;
    dim3 blk(256);
    dim3 gD(D_ / 128, M / 128);
    dim3 gQKV(D_ / 128, M / 128, 3);
    dim3 gF(DFF_ / 128, M / 128);

    split_rows<<<n4act / 256, blk, 0, stream>>>(Q, Qh, Ql, n4act);
    split_rows<<<n4act / 256, blk, 0, stream>>>(K, Kh, Kl, n4act);
    split_tr<<<dim3(D_/32, D_/32), blk, 0, stream>>>(Wq, Wqh, Wql, D_, D_);
    split_tr<<<dim3(D_/32, D_/32), blk, 0, stream>>>(Wk, Wkh, Wkl, D_, D_);
    split_tr<<<dim3(D_/32, D_/32), blk, 0, stream>>>(Wv, Wvh, Wvl, D_, D_);
    split_tr<<<dim3(D_/32, D_/32), blk, 0, stream>>>(Wo, Woh, Wol, D_, D_);

    QkvArgs qa;
    qa.Ah[0] = Qh;  qa.Al[0] = Ql;  qa.Bh[0] = Wqh; qa.Bl[0] = Wql; qa.bias[0] = bq; qa.Co[0] = qhp;
    qa.Ah[1] = Kh;  qa.Al[1] = Kl;  qa.Bh[1] = Wkh; qa.Bl[1] = Wkl; qa.bias[1] = bk; qa.Co[1] = khp;
    qa.Ah[2] = Kh;  qa.Al[2] = Kl;  qa.Bh[2] = Wvh; qa.Bl[2] = Wvl; qa.bias[2] = bv; qa.Co[2] = vhp;
    gemm_qkv<<<gQKV, blk, 0, stream>>>(qa, M, D_, D_);

    flash_attn_mfma<<<dim3(1024), blk, 0, stream>>>(qhp, khp, vhp, aOh, aOl);

    gemm_mfma<false,0><<<gD, blk, 0, stream>>>(aOh, aOl, Woh, Wol, bo, oprj, nullptr, nullptr, M, D_, D_);
    add_ln<true><<<M, blk, 0, stream>>>(oprj, Q, g0, be0, Xf, Xh, Xl);

    split_tr<<<dim3(DFF_/32, D_/32), blk, 0, stream>>>(W1, W1h, W1l, D_, DFF_);
    gemm_mfma<true,1><<<gF, blk, 0, stream>>>(Xh, Xl, W1h, W1l, b1, nullptr, Hih, Hil, M, DFF_, D_);
    split_tr<<<dim3(D_/32, DFF_/32), blk, 0, stream>>>(W2, W2h, W2l, DFF_, D_);
    gemm_mfma<false,0><<<gD, blk, 0, stream>>>(Hih, Hil, W2h, W2l, b2, Y, nullptr, nullptr, M, D_, DFF_);
    add_ln<false><<<M, blk, 0, stream>>>(Y, Xf, g1, be1, (float*)d_out, nullptr, nullptr);
}

// Round 10
// 473.158 us; speedup vs baseline: 1.1698x; 1.0288x over previous
//
#include <hip/hip_runtime.h>
#include <math.h>

#define B_   4
#define NQ_  1024
#define NK_  1024
#define D_   1024
#define H_   16
#define DH_  64
#define DFF_ 4096
#define SCALE_ (1.0f/32.0f)   // 1/sqrt(D)
#define LN_EPS_ 1e-5f

typedef __attribute__((ext_vector_type(8))) short bf16x8_t;  // 8 bf16 = 4 VGPR
typedef __attribute__((ext_vector_type(4))) float f32x4_t;

__device__ __forceinline__ ushort f2bf_rne(float x) {
    unsigned u = __float_as_uint(x);
    unsigned r = (u + 0x7FFFu + ((u >> 16) & 1u)) >> 16;
    return (ushort)r;
}
__device__ __forceinline__ float bf2f(ushort h) {
    return __uint_as_float(((unsigned)h) << 16);
}

// async global->LDS, 16B per lane. LDS dest = wave-uniform base + lane*16.
__device__ __forceinline__ void gl_lds16(const ushort* g, ushort* l) {
    __builtin_amdgcn_global_load_lds(
        (const __attribute__((address_space(1))) unsigned int*)g,
        (__attribute__((address_space(3))) unsigned int*)l, 16, 0, 0);
}

// ---------------------------------------------------------------------------
// fp32 -> (hi,lo) bf16 planes.
// ---------------------------------------------------------------------------
__global__ __launch_bounds__(256) void split_rows(const float* __restrict__ src,
        ushort* __restrict__ hi, ushort* __restrict__ lo, int n4)
{
    int i = blockIdx.x * 256 + threadIdx.x;
    if (i >= n4) return;
    float4 v = ((const float4*)src)[i];
    ushort4 h, l;
    h.x = f2bf_rne(v.x); l.x = f2bf_rne(v.x - bf2f(h.x));
    h.y = f2bf_rne(v.y); l.y = f2bf_rne(v.y - bf2f(h.y));
    h.z = f2bf_rne(v.z); l.z = f2bf_rne(v.z - bf2f(h.z));
    h.w = f2bf_rne(v.w); l.w = f2bf_rne(v.w - bf2f(h.w));
    ((ushort4*)hi)[i] = h;
    ((ushort4*)lo)[i] = l;
}

// ---------------------------------------------------------------------------
// Weight split + transpose: W[K][N] fp32 -> planes Wt[N][K] bf16.
// ---------------------------------------------------------------------------
__global__ __launch_bounds__(256) void split_tr(const float* __restrict__ Wsrc,
        ushort* __restrict__ th, ushort* __restrict__ tl, int K, int N)
{
    __shared__ float tile[32][33];
    const int nb = blockIdx.x * 32, kb = blockIdx.y * 32;
    const int t = threadIdx.x;
    {
        int r = t >> 3, c4 = (t & 7) * 4;
        float4 v = *(const float4*)&Wsrc[(size_t)(kb + r) * N + nb + c4];
        tile[r][c4 + 0] = v.x; tile[r][c4 + 1] = v.y;
        tile[r][c4 + 2] = v.z; tile[r][c4 + 3] = v.w;
    }
    __syncthreads();
    {
        int n = t >> 3, k4 = (t & 7) * 4;
        float a0 = tile[k4 + 0][n], a1 = tile[k4 + 1][n];
        float a2 = tile[k4 + 2][n], a3 = tile[k4 + 3][n];
        ushort4 h, l;
        h.x = f2bf_rne(a0); l.x = f2bf_rne(a0 - bf2f(h.x));
        h.y = f2bf_rne(a1); l.y = f2bf_rne(a1 - bf2f(h.y));
        h.z = f2bf_rne(a2); l.z = f2bf_rne(a2 - bf2f(h.z));
        h.w = f2bf_rne(a3); l.w = f2bf_rne(a3 - bf2f(h.w));
        size_t o = (size_t)(nb + n) * K + kb + k4;
        *(ushort4*)&th[o] = h;
        *(ushort4*)&tl[o] = l;
    }
}

// ---------------------------------------------------------------------------
// MFMA GEMM, split-bf16 operands. r10: counted-vmcnt fine-phase pipeline
// (m201-style T3+T4 at 128^2): 3 phases/K-tile (terms hh, hl, lh; 16 MFMA
// each). Plane-group ring G0=[Ah,Bh] G1=[Bl] G2=[Al]; per-wave loads
// 4/2/2 per group. Steady-state waits vmcnt(6)/(6)/(4) — never 0 in loop.
// LDS 64KB dbuf (2 blocks/CU). Arithmetic bit-identical to r9 (same frag
// reads, same per-element accumulate order hh,hl,lh).
// OMODE: 0 = fp32 out, 1 = split planes out, 2 = hi-only bf16 out
// (1/2 use the coalesced LDS-bounce epilogue validated r9).
// ---------------------------------------------------------------------------
template<bool RELU, int OMODE>
__device__ __forceinline__ void gemm_body(
        const ushort* __restrict__ Ah, const ushort* __restrict__ Al,
        const ushort* __restrict__ Bh, const ushort* __restrict__ Bl,
        const float* __restrict__ bias,
        float* __restrict__ C, ushort* __restrict__ Ch, ushort* __restrict__ Cl,
        int M, int N, int Kd, int brow, int bcol)
{
    __shared__ __align__(16) ushort S[2][4][128 * 32];   // 64KB dbuf

    const int t    = threadIdx.x;
    const int lane = t & 63;
    const int w    = t >> 6;
    const int wr   = (w >> 1) * 64;
    const int wc   = (w & 1) * 64;
    const int fr   = lane & 15;
    const int g    = lane >> 4;
    const int sS   = ((g ^ ((fr >> 1) & 3)) << 3);
    const int cl   = lane & 15;
    const int rq   = (lane >> 4) * 4;

    // bias preload: keeps the K-loop free of stray VMEM ops (vmcnt counts!)
    float bpre[4];
    #pragma unroll
    for (int j = 0; j < 4; ++j) bpre[j] = bias[bcol + wc + j * 16 + cl];

    f32x4_t acc[4][4];
    #pragma unroll
    for (int i = 0; i < 4; ++i)
        #pragma unroll
        for (int j = 0; j < 4; ++j)
            acc[i][j] = (f32x4_t){0.f, 0.f, 0.f, 0.f};

    const int lrow  = lane >> 2;
    const int lslot = ((lane & 3) ^ ((lane >> 3) & 3)) << 3;
    const int c0    = w * 2;   // this wave's 2 chunks (16 rows each) per plane

    auto issue2 = [&](const ushort* gpp, int rb, int pl, int buf, int k0) {
        #pragma unroll
        for (int ii = 0; ii < 2; ++ii) {
            int c = c0 + ii;
            gl_lds16(gpp + (size_t)(rb + c * 16 + lrow) * Kd + k0 + lslot,
                     &S[buf][pl][c * 512]);
        }
    };

    bf16x8_t ahf[4], bhf[4], blf[4], alf[4];

    // prologue: tile 0 into buf 0, issue order G0=[Ah,Bh], G1=[Bl], G2=[Al]
    issue2(Ah, brow, 0, 0, 0);
    issue2(Bh, bcol, 2, 0, 0);
    issue2(Bl, bcol, 3, 0, 0);
    issue2(Al, brow, 1, 0, 0);
    asm volatile("s_waitcnt vmcnt(4)" ::: "memory");   // G0(tile0) done
    __builtin_amdgcn_s_barrier();

    const int NT = Kd >> 5;
    for (int tt = 0; tt < NT; ++tt) {
        const int cur = tt & 1, nxt = cur ^ 1;
        const int kn  = (tt + 1) << 5;
        const bool more = (tt + 1 < NT);

        // ---- phase 0: hh — read Ah,Bh(cur); issue G0(t+1); confirm G1(t)
        #pragma unroll
        for (int i = 0; i < 4; ++i)
            ahf[i] = *(const bf16x8_t*)&S[cur][0][(wr + i * 16 + fr) * 32 + sS];
        #pragma unroll
        for (int j = 0; j < 4; ++j)
            bhf[j] = *(const bf16x8_t*)&S[cur][2][(wc + j * 16 + fr) * 32 + sS];
        if (more) {
            issue2(Ah, brow, 0, nxt, kn);
            issue2(Bh, bcol, 2, nxt, kn);
            asm volatile("s_waitcnt vmcnt(6)" ::: "memory");
        } else {
            asm volatile("s_waitcnt vmcnt(2)" ::: "memory");
        }
        __builtin_amdgcn_s_barrier();
        asm volatile("s_waitcnt lgkmcnt(0)" ::: "memory");
        __builtin_amdgcn_sched_barrier(0);
        __builtin_amdgcn_s_setprio(1);
        #pragma unroll
        for (int i = 0; i < 4; ++i)
            #pragma unroll
            for (int j = 0; j < 4; ++j)
                acc[i][j] = __builtin_amdgcn_mfma_f32_16x16x32_bf16(ahf[i], bhf[j], acc[i][j], 0, 0, 0);
        __builtin_amdgcn_s_setprio(0);
        __builtin_amdgcn_s_barrier();

        // ---- phase 1: hl — read Bl(cur); issue G1(t+1); confirm G2(t)
        #pragma unroll
        for (int j = 0; j < 4; ++j)
            blf[j] = *(const bf16x8_t*)&S[cur][3][(wc + j * 16 + fr) * 32 + sS];
        if (more) {
            issue2(Bl, bcol, 3, nxt, kn);
            asm volatile("s_waitcnt vmcnt(6)" ::: "memory");
        } else {
            asm volatile("s_waitcnt vmcnt(0)" ::: "memory");
        }
        __builtin_amdgcn_s_barrier();
        asm volatile("s_waitcnt lgkmcnt(0)" ::: "memory");
        __builtin_amdgcn_sched_barrier(0);
        __builtin_amdgcn_s_setprio(1);
        #pragma unroll
        for (int i = 0; i < 4; ++i)
            #pragma unroll
            for (int j = 0; j < 4; ++j)
                acc[i][j] = __builtin_amdgcn_mfma_f32_16x16x32_bf16(ahf[i], blf[j], acc[i][j], 0, 0, 0);
        __builtin_amdgcn_s_setprio(0);
        __builtin_amdgcn_s_barrier();

        // ---- phase 2: lh — read Al(cur); issue G2(t+1); confirm G0(t+1)
        #pragma unroll
        for (int i = 0; i < 4; ++i)
            alf[i] = *(const bf16x8_t*)&S[cur][1][(wr + i * 16 + fr) * 32 + sS];
        if (more) {
            issue2(Al, brow, 1, nxt, kn);
            asm volatile("s_waitcnt vmcnt(4)" ::: "memory");
        }
        __builtin_amdgcn_s_barrier();
        asm volatile("s_waitcnt lgkmcnt(0)" ::: "memory");
        __builtin_amdgcn_sched_barrier(0);
        __builtin_amdgcn_s_setprio(1);
        #pragma unroll
        for (int i = 0; i < 4; ++i)
            #pragma unroll
            for (int j = 0; j < 4; ++j)
                acc[i][j] = __builtin_amdgcn_mfma_f32_16x16x32_bf16(alf[i], bhf[j], acc[i][j], 0, 0, 0);
        __builtin_amdgcn_s_setprio(0);
        __builtin_amdgcn_s_barrier();
    }

    // ---- epilogue (r9-validated) ----
    if (OMODE == 0) {
        #pragma unroll
        for (int j = 0; j < 4; ++j) {
            int col = bcol + wc + j * 16 + cl;
            #pragma unroll
            for (int i = 0; i < 4; ++i)
                #pragma unroll
                for (int r = 0; r < 4; ++r) {
                    int row = brow + wr + i * 16 + rq + r;
                    float v = acc[i][j][r] + bpre[j];
                    if (RELU) v = fmaxf(v, 0.f);
                    C[(size_t)row * N + col] = v;
                }
        }
    } else {
        // coalesced bounce: wave-private 64x64 f32 view over staging LDS
        float* E = (float*)&S[0][0][0] + w * 4096;   // 16KB per wave
        #pragma unroll
        for (int j = 0; j < 4; ++j) {
            #pragma unroll
            for (int i = 0; i < 4; ++i)
                #pragma unroll
                for (int r = 0; r < 4; ++r) {
                    float v = acc[i][j][r] + bpre[j];
                    if (RELU) v = fmaxf(v, 0.f);
                    E[(i * 16 + rq + r) * 64 + j * 16 + cl] = v;
                }
        }
        __syncthreads();
        const int rr8 = lane >> 3;          // 0..7
        const int c8  = (lane & 7) * 8;     // col base (8 f32 = 32B aligned)
        #pragma unroll
        for (int p = 0; p < 8; ++p) {
            int rl = p * 8 + rr8;
            float4 va = *(float4*)&E[rl * 64 + c8];
            float4 vb = *(float4*)&E[rl * 64 + c8 + 4];
            float v[8] = {va.x, va.y, va.z, va.w, vb.x, vb.y, vb.z, vb.w};
            bf16x8_t hv, lv;
            #pragma unroll
            for (int q = 0; q < 8; ++q) {
                ushort hh = f2bf_rne(v[q]);
                hv[q] = (short)hh;
                lv[q] = (short)f2bf_rne(v[q] - bf2f(hh));
            }
            size_t o = (size_t)(brow + wr + rl) * N + (bcol + wc + c8);
            *(bf16x8_t*)&Ch[o] = hv;
            if (OMODE == 1) *(bf16x8_t*)&Cl[o] = lv;
        }
    }
}

// bijective XCD-chunked swizzle (nwg % 8 == 0 for all our grids)
__device__ __forceinline__ void swz_block(int& brow, int& bcol, int tile) {
    const int nx  = gridDim.x;
    const int lin = blockIdx.y * nx + blockIdx.x;
    const int cpx = (nx * gridDim.y) >> 3;
    const int swz = (lin & 7) * cpx + (lin >> 3);
    brow = (swz / nx) * tile;
    bcol = (swz % nx) * tile;
}

template<bool RELU, int OMODE>
__global__ __launch_bounds__(256) void gemm_mfma(
        const ushort* __restrict__ Ah, const ushort* __restrict__ Al,
        const ushort* __restrict__ Bh, const ushort* __restrict__ Bl,
        const float* __restrict__ bias,
        float* __restrict__ C, ushort* __restrict__ Ch, ushort* __restrict__ Cl,
        int M, int N, int Kd)
{
    int brow, bcol;
    swz_block(brow, bcol, 128);
    gemm_body<RELU, OMODE>(Ah, Al, Bh, Bl, bias, C, Ch, Cl, M, N, Kd, brow, bcol);
}

// q/k/v projections fused into one dispatch (grid.z = 3 -> 768 blocks)
struct QkvArgs {
    const ushort* Ah[3]; const ushort* Al[3];
    const ushort* Bh[3]; const ushort* Bl[3];
    const float*  bias[3];
    ushort*       Co[3];
};

__global__ __launch_bounds__(256) void gemm_qkv(QkvArgs qa, int M, int N, int Kd)
{
    int brow, bcol;
    swz_block(brow, bcol, 128);
    const int z = blockIdx.z;
    gemm_body<false, 2>(qa.Ah[z], qa.Al[z], qa.Bh[z], qa.Bl[z], qa.bias[z],
                        nullptr, qa.Co[z], nullptr, M, N, Kd, brow, bcol);
}

// ---------------------------------------------------------------------------
// MFMA flash attention (validated round 4). 1024 blocks, 4 waves, QBLK=64,
// KVBLK=32; online softmax via 16-lane shfl_xor; output split planes.
// ---------------------------------------------------------------------------
__global__ __launch_bounds__(256) void flash_attn_mfma(
        const ushort* __restrict__ qh, const ushort* __restrict__ kh,
        const ushort* __restrict__ vh,
        ushort* __restrict__ Oh, ushort* __restrict__ Ol)
{
    __shared__ __align__(16) ushort sk[32 * 72];
    __shared__ __align__(16) ushort svt[64 * 40];
    __shared__ __align__(16) ushort pbuf[4][16 * 40];

    const int bid  = blockIdx.x;
    const int slot = bid >> 3;
    const int bh   = (bid & 7) * 8 + (slot >> 4);
    const int qt   = slot & 15;
    const int b    = bh >> 4;
    const int h    = bh & 15;
    const int qb   = qt * 64;

    const int t = threadIdx.x, lane = t & 63, w = t >> 6;
    const int l15 = lane & 15, g = lane >> 4;

    bf16x8_t qf[2];
    {
        size_t qrow = ((size_t)(b * NQ_) + qb + w * 16 + l15) * D_ + h * DH_;
        qf[0] = *(const bf16x8_t*)&qh[qrow + 0  + 8 * g];
        qf[1] = *(const bf16x8_t*)&qh[qrow + 32 + 8 * g];
    }

    f32x4_t acc[4];
    #pragma unroll
    for (int dt = 0; dt < 4; ++dt) acc[dt] = (f32x4_t){0.f, 0.f, 0.f, 0.f};
    float m[4]    = {-INFINITY, -INFINITY, -INFINITY, -INFINITY};
    float lsum[4] = {0.f, 0.f, 0.f, 0.f};

    const int kkv = t >> 3,  kds = (t & 7) * 8;
    const int vkv = t & 31,  vds = (t >> 5) * 8;
    const size_t kvbase = (size_t)(b * NK_) * D_ + h * DH_;

    for (int kt = 0; kt < NK_; kt += 32) {
        __syncthreads();
        {
            bf16x8_t kk = *(const bf16x8_t*)&kh[kvbase + (size_t)(kt + kkv) * D_ + kds];
            *(bf16x8_t*)&sk[kkv * 72 + kds] = kk;
            bf16x8_t vv = *(const bf16x8_t*)&vh[kvbase + (size_t)(kt + vkv) * D_ + vds];
            #pragma unroll
            for (int j = 0; j < 8; ++j)
                svt[(vds + j) * 40 + vkv] = (ushort)vv[j];
        }
        __syncthreads();

        f32x4_t s0 = (f32x4_t){0.f,0.f,0.f,0.f};
        f32x4_t s1 = (f32x4_t){0.f,0.f,0.f,0.f};
        #pragma unroll
        for (int c = 0; c < 2; ++c) {
            bf16x8_t k0 = *(const bf16x8_t*)&sk[(l15     ) * 72 + 32 * c + 8 * g];
            bf16x8_t k1 = *(const bf16x8_t*)&sk[(l15 + 16) * 72 + 32 * c + 8 * g];
            s0 = __builtin_amdgcn_mfma_f32_16x16x32_bf16(qf[c], k0, s0, 0, 0, 0);
            s1 = __builtin_amdgcn_mfma_f32_16x16x32_bf16(qf[c], k1, s1, 0, 0, 0);
        }

        float p0[4], p1[4], corr[4];
        #pragma unroll
        for (int r = 0; r < 4; ++r) {
            float e0 = s0[r] * SCALE_, e1 = s1[r] * SCALE_;
            float tm = fmaxf(e0, e1);
            tm = fmaxf(tm, __shfl_xor(tm, 1, 64));
            tm = fmaxf(tm, __shfl_xor(tm, 2, 64));
            tm = fmaxf(tm, __shfl_xor(tm, 4, 64));
            tm = fmaxf(tm, __shfl_xor(tm, 8, 64));
            float mn = fmaxf(m[r], tm);
            corr[r] = __expf(m[r] - mn);
            p0[r] = __expf(e0 - mn);
            p1[r] = __expf(e1 - mn);
            float ps = p0[r] + p1[r];
            ps += __shfl_xor(ps, 1, 64);
            ps += __shfl_xor(ps, 2, 64);
            ps += __shfl_xor(ps, 4, 64);
            ps += __shfl_xor(ps, 8, 64);
            lsum[r] = lsum[r] * corr[r] + ps;
            m[r] = mn;
        }
        #pragma unroll
        for (int dt = 0; dt < 4; ++dt)
            #pragma unroll
            for (int r = 0; r < 4; ++r)
                acc[dt][r] *= corr[r];

        ushort* pw = &pbuf[w][0];
        #pragma unroll
        for (int r = 0; r < 4; ++r) {
            pw[(4 * g + r) * 40 + l15     ] = f2bf_rne(p0[r]);
            pw[(4 * g + r) * 40 + l15 + 16] = f2bf_rne(p1[r]);
        }
        bf16x8_t pa = *(const bf16x8_t*)&pw[l15 * 40 + 8 * g];

        #pragma unroll
        for (int dt = 0; dt < 4; ++dt) {
            bf16x8_t vf = *(const bf16x8_t*)&svt[(16 * dt + l15) * 40 + 8 * g];
            acc[dt] = __builtin_amdgcn_mfma_f32_16x16x32_bf16(pa, vf, acc[dt], 0, 0, 0);
        }
    }

    float inv[4];
    #pragma unroll
    for (int r = 0; r < 4; ++r) inv[r] = 1.0f / lsum[r];
    #pragma unroll
    for (int dt = 0; dt < 4; ++dt) {
        #pragma unroll
        for (int r = 0; r < 4; ++r) {
            int row = b * NQ_ + qb + w * 16 + 4 * g + r;
            int col = h * DH_ + 16 * dt + l15;
            float v = acc[dt][r] * inv[r];
            ushort hh = f2bf_rne(v);
            Oh[(size_t)row * D_ + col] = hh;
            Ol[(size_t)row * D_ + col] = f2bf_rne(v - bf2f(hh));
        }
    }
}

// ---------------------------------------------------------------------------
// out = LayerNorm(a + r) * g + be. SPLIT: also emit bf16 hi/lo planes.
// ---------------------------------------------------------------------------
template<bool SPLIT>
__global__ __launch_bounds__(256) void add_ln(const float* __restrict__ a,
        const float* __restrict__ r, const float* __restrict__ g,
        const float* __restrict__ be, float* __restrict__ out,
        ushort* __restrict__ oh, ushort* __restrict__ ol)
{
    const int row = blockIdx.x;
    const int t = threadIdx.x;
    float vals[4];
    float s1 = 0.0f, s2 = 0.0f;
    #pragma unroll
    for (int i = 0; i < 4; ++i) {
        int col = t + i * 256;
        float vv = a[(size_t)row * D_ + col] + r[(size_t)row * D_ + col];
        vals[i] = vv;
        s1 += vv;
        s2 += vv * vv;
    }
    #pragma unroll
    for (int off = 32; off > 0; off >>= 1) {
        s1 += __shfl_down(s1, off, 64);
        s2 += __shfl_down(s2, off, 64);
    }
    __shared__ float p1[4], p2[4];
    const int wave = t >> 6;
    if ((t & 63) == 0) { p1[wave] = s1; p2[wave] = s2; }
    __syncthreads();
    s1 = p1[0] + p1[1] + p1[2] + p1[3];
    s2 = p2[0] + p2[1] + p2[2] + p2[3];
    const float mean = s1 * (1.0f / D_);
    const float var  = s2 * (1.0f / D_) - mean * mean;
    const float rstd = rsqrtf(var + LN_EPS_);
    #pragma unroll
    for (int i = 0; i < 4; ++i) {
        int col = t + i * 256;
        float v = (vals[i] - mean) * rstd * g[col] + be[col];
        out[(size_t)row * D_ + col] = v;
        if (SPLIT) {
            ushort h = f2bf_rne(v);
            oh[(size_t)row * D_ + col] = h;
            ol[(size_t)row * D_ + col] = f2bf_rne(v - bf2f(h));
        }
    }
}

// ---------------------------------------------------------------------------
extern "C" void kernel_launch(void* const* d_in, const int* in_sizes, int n_in,
                              void* d_out, int out_size, void* d_ws, size_t ws_size,
                              hipStream_t stream)
{
    const float* Q   = (const float*)d_in[0];
    const float* K   = (const float*)d_in[1];
    const float* Wq  = (const float*)d_in[2];
    const float* bq  = (const float*)d_in[3];
    const float* Wk  = (const float*)d_in[4];
    const float* bk  = (const float*)d_in[5];
    const float* Wv  = (const float*)d_in[6];
    const float* bv  = (const float*)d_in[7];
    const float* Wo  = (const float*)d_in[8];
    const float* bo  = (const float*)d_in[9];
    const float* W1  = (const float*)d_in[10];
    const float* b1  = (const float*)d_in[11];
    const float* W2  = (const float*)d_in[12];
    const float* b2  = (const float*)d_in[13];
    const float* g0  = (const float*)d_in[14];
    const float* be0 = (const float*)d_in[15];
    const float* g1  = (const float*)d_in[16];
    const float* be1 = (const float*)d_in[17];

    unsigned char* Wb = (unsigned char*)d_ws;
    const size_t MBy = 1ull << 20;

    ushort* Qh  = (ushort*)(Wb +  0 * MBy);
    ushort* Ql  = (ushort*)(Wb +  8 * MBy);
    ushort* Kh  = (ushort*)(Wb + 16 * MBy);
    ushort* Kl  = (ushort*)(Wb + 24 * MBy);
    ushort* Wqh = (ushort*)(Wb + 32 * MBy);
    ushort* Wql = (ushort*)(Wb + 34 * MBy);
    ushort* Wkh = (ushort*)(Wb + 36 * MBy);
    ushort* Wkl = (ushort*)(Wb + 38 * MBy);
    ushort* Wvh = (ushort*)(Wb + 40 * MBy);
    ushort* Wvl = (ushort*)(Wb + 42 * MBy);
    ushort* Woh = (ushort*)(Wb + 44 * MBy);
    ushort* Wol = (ushort*)(Wb + 46 * MBy);
    ushort* qhp = (ushort*)(Wb + 48 * MBy);
    ushort* khp = (ushort*)(Wb + 56 * MBy);
    ushort* vhp = (ushort*)(Wb + 64 * MBy);
    ushort* aOh = (ushort*)(Wb + 72 * MBy);
    ushort* aOl = (ushort*)(Wb + 80 * MBy);

    float*  oprj = (float*)(Wb + 16 * MBy);
    float*  Xf   = (float*)(Wb +  0 * MBy);
    ushort* Xh   = (ushort*)(Wb + 48 * MBy);
    ushort* Xl   = (ushort*)(Wb + 56 * MBy);
    ushort* W1h  = (ushort*)(Wb + 64 * MBy);
    ushort* W1l  = (ushort*)(Wb + 72 * MBy);
    ushort* Hih  = (ushort*)(Wb + 80 * MBy);   // 32MB
    ushort* Hil  = (ushort*)(Wb + 16 * MBy);   // 32MB
    ushort* W2h  = (ushort*)(Wb + 48 * MBy);
    ushort* W2l  = (ushort*)(Wb + 56 * MBy);
    float*  Y    = (float*)(Wb + 64 * MBy);

    const int M = B_ * NQ_;
    const int n4act = M * D_ / 4;
    dim3 blk(256);
    dim3 gD(D_ / 128, M / 128);
    dim3 gQKV(D_ / 128, M / 128, 3);
    dim3 gF(DFF_ / 128, M / 128);

    split_rows<<<n4act / 256, blk, 0, stream>>>(Q, Qh, Ql, n4act);
    split_rows<<<n4act / 256, blk, 0, stream>>>(K, Kh, Kl, n4act);
    split_tr<<<dim3(D_/32, D_/32), blk, 0, stream>>>(Wq, Wqh, Wql, D_, D_);
    split_tr<<<dim3(D_/32, D_/32), blk, 0, stream>>>(Wk, Wkh, Wkl, D_, D_);
    split_tr<<<dim3(D_/32, D_/32), blk, 0, stream>>>(Wv, Wvh, Wvl, D_, D_);
    split_tr<<<dim3(D_/32, D_/32), blk, 0, stream>>>(Wo, Woh, Wol, D_, D_);

    QkvArgs qa;
    qa.Ah[0] = Qh;  qa.Al[0] = Ql;  qa.Bh[0] = Wqh; qa.Bl[0] = Wql; qa.bias[0] = bq; qa.Co[0] = qhp;
    qa.Ah[1] = Kh;  qa.Al[1] = Kl;  qa.Bh[1] = Wkh; qa.Bl[1] = Wkl; qa.bias[1] = bk; qa.Co[1] = khp;
    qa.Ah[2] = Kh;  qa.Al[2] = Kl;  qa.Bh[2] = Wvh; qa.Bl[2] = Wvl; qa.bias[2] = bv; qa.Co[2] = vhp;
    gemm_qkv<<<gQKV, blk, 0, stream>>>(qa, M, D_, D_);

    flash_attn_mfma<<<dim3(1024), blk, 0, stream>>>(qhp, khp, vhp, aOh, aOl);

    gemm_mfma<false,0><<<gD, blk, 0, stream>>>(aOh, aOl, Woh, Wol, bo, oprj, nullptr, nullptr, M, D_, D_);
    add_ln<true><<<M, blk, 0, stream>>>(oprj, Q, g0, be0, Xf, Xh, Xl);

    split_tr<<<dim3(DFF_/32, D_/32), blk, 0, stream>>>(W1, W1h, W1l, D_, DFF_);
    gemm_mfma<true,1><<<gF, blk, 0, stream>>>(Xh, Xl, W1h, W1l, b1, nullptr, Hih, Hil, M, DFF_, D_);
    split_tr<<<dim3(D_/32, DFF_/32), blk, 0, stream>>>(W2, W2h, W2l, DFF_, D_);
    gemm_mfma<false,0><<<gD, blk, 0, stream>>>(Hih, Hil, W2h, W2l, b2, Y, nullptr, nullptr, M, D_, DFF_);
    add_ln<false><<<M, blk, 0, stream>>>(Y, Xf, g1, be1, (float*)d_out, nullptr, nullptr);
}

// Round 11
// 453.077 us; speedup vs baseline: 1.2217x; 1.0443x over previous
//
#include <hip/hip_runtime.h>
#include <math.h>

#define B_   4
#define NQ_  1024
#define NK_  1024
#define D_   1024
#define H_   16
#define DH_  64
#define DFF_ 4096
#define SCALE_ (1.0f/32.0f)   // 1/sqrt(D)
#define LN_EPS_ 1e-5f

typedef __attribute__((ext_vector_type(8))) short bf16x8_t;  // 8 bf16 = 4 VGPR
typedef __attribute__((ext_vector_type(4))) float f32x4_t;

__device__ __forceinline__ ushort f2bf_rne(float x) {
    unsigned u = __float_as_uint(x);
    unsigned r = (u + 0x7FFFu + ((u >> 16) & 1u)) >> 16;
    return (ushort)r;
}
__device__ __forceinline__ float bf2f(ushort h) {
    return __uint_as_float(((unsigned)h) << 16);
}

// async global->LDS, 16B per lane. LDS dest = wave-uniform base + lane*16.
__device__ __forceinline__ void gl_lds16(const ushort* g, ushort* l) {
    __builtin_amdgcn_global_load_lds(
        (const __attribute__((address_space(1))) unsigned int*)g,
        (__attribute__((address_space(3))) unsigned int*)l, 16, 0, 0);
}

// ---------------------------------------------------------------------------
// fp32 -> (hi,lo) bf16 planes.
// ---------------------------------------------------------------------------
__global__ __launch_bounds__(256) void split_rows(const float* __restrict__ src,
        ushort* __restrict__ hi, ushort* __restrict__ lo, int n4)
{
    int i = blockIdx.x * 256 + threadIdx.x;
    if (i >= n4) return;
    float4 v = ((const float4*)src)[i];
    ushort4 h, l;
    h.x = f2bf_rne(v.x); l.x = f2bf_rne(v.x - bf2f(h.x));
    h.y = f2bf_rne(v.y); l.y = f2bf_rne(v.y - bf2f(h.y));
    h.z = f2bf_rne(v.z); l.z = f2bf_rne(v.z - bf2f(h.z));
    h.w = f2bf_rne(v.w); l.w = f2bf_rne(v.w - bf2f(h.w));
    ((ushort4*)hi)[i] = h;
    ((ushort4*)lo)[i] = l;
}

// ---------------------------------------------------------------------------
// Weight split + transpose: W[K][N] fp32 -> planes Wt[N][K] bf16.
// ---------------------------------------------------------------------------
__global__ __launch_bounds__(256) void split_tr(const float* __restrict__ Wsrc,
        ushort* __restrict__ th, ushort* __restrict__ tl, int K, int N)
{
    __shared__ float tile[32][33];
    const int nb = blockIdx.x * 32, kb = blockIdx.y * 32;
    const int t = threadIdx.x;
    {
        int r = t >> 3, c4 = (t & 7) * 4;
        float4 v = *(const float4*)&Wsrc[(size_t)(kb + r) * N + nb + c4];
        tile[r][c4 + 0] = v.x; tile[r][c4 + 1] = v.y;
        tile[r][c4 + 2] = v.z; tile[r][c4 + 3] = v.w;
    }
    __syncthreads();
    {
        int n = t >> 3, k4 = (t & 7) * 4;
        float a0 = tile[k4 + 0][n], a1 = tile[k4 + 1][n];
        float a2 = tile[k4 + 2][n], a3 = tile[k4 + 3][n];
        ushort4 h, l;
        h.x = f2bf_rne(a0); l.x = f2bf_rne(a0 - bf2f(h.x));
        h.y = f2bf_rne(a1); l.y = f2bf_rne(a1 - bf2f(h.y));
        h.z = f2bf_rne(a2); l.z = f2bf_rne(a2 - bf2f(h.z));
        h.w = f2bf_rne(a3); l.w = f2bf_rne(a3 - bf2f(h.w));
        size_t o = (size_t)(nb + n) * K + kb + k4;
        *(ushort4*)&th[o] = h;
        *(ushort4*)&tl[o] = l;
    }
}

// ---------------------------------------------------------------------------
// MFMA GEMM body (r10-validated counted-vmcnt fine-phase pipeline).
// Kd = row stride; Klen = K extent of this block's work (split-K window).
// bias == nullptr -> no bias. OMODE: 0 fp32, 1 split planes, 2 hi-only.
// ---------------------------------------------------------------------------
template<bool RELU, int OMODE>
__device__ __forceinline__ void gemm_body(
        const ushort* __restrict__ Ah, const ushort* __restrict__ Al,
        const ushort* __restrict__ Bh, const ushort* __restrict__ Bl,
        const float* __restrict__ bias,
        float* __restrict__ C, ushort* __restrict__ Ch, ushort* __restrict__ Cl,
        int M, int N, int Kd, int Klen, int brow, int bcol)
{
    __shared__ __align__(16) ushort S[2][4][128 * 32];   // 64KB dbuf

    const int t    = threadIdx.x;
    const int lane = t & 63;
    const int w    = t >> 6;
    const int wr   = (w >> 1) * 64;
    const int wc   = (w & 1) * 64;
    const int fr   = lane & 15;
    const int g    = lane >> 4;
    const int sS   = ((g ^ ((fr >> 1) & 3)) << 3);
    const int cl   = lane & 15;
    const int rq   = (lane >> 4) * 4;

    // bias preload (issued before staging so it drains with prologue G0)
    float bpre[4];
    #pragma unroll
    for (int j = 0; j < 4; ++j)
        bpre[j] = bias ? bias[bcol + wc + j * 16 + cl] : 0.f;

    f32x4_t acc[4][4];
    #pragma unroll
    for (int i = 0; i < 4; ++i)
        #pragma unroll
        for (int j = 0; j < 4; ++j)
            acc[i][j] = (f32x4_t){0.f, 0.f, 0.f, 0.f};

    const int lrow  = lane >> 2;
    const int lslot = ((lane & 3) ^ ((lane >> 3) & 3)) << 3;
    const int c0    = w * 2;   // this wave's 2 chunks (16 rows each) per plane

    auto issue2 = [&](const ushort* gpp, int rb, int pl, int buf, int k0) {
        #pragma unroll
        for (int ii = 0; ii < 2; ++ii) {
            int c = c0 + ii;
            gl_lds16(gpp + (size_t)(rb + c * 16 + lrow) * Kd + k0 + lslot,
                     &S[buf][pl][c * 512]);
        }
    };

    bf16x8_t ahf[4], bhf[4], blf[4], alf[4];

    // prologue: tile 0 into buf 0, issue order G0=[Ah,Bh], G1=[Bl], G2=[Al]
    issue2(Ah, brow, 0, 0, 0);
    issue2(Bh, bcol, 2, 0, 0);
    issue2(Bl, bcol, 3, 0, 0);
    issue2(Al, brow, 1, 0, 0);
    asm volatile("s_waitcnt vmcnt(4)" ::: "memory");   // G0(tile0) done
    __builtin_amdgcn_s_barrier();

    const int NT = Klen >> 5;
    for (int tt = 0; tt < NT; ++tt) {
        const int cur = tt & 1, nxt = cur ^ 1;
        const int kn  = (tt + 1) << 5;
        const bool more = (tt + 1 < NT);

        // ---- phase 0: hh — read Ah,Bh(cur); issue G0(t+1); confirm G1(t)
        #pragma unroll
        for (int i = 0; i < 4; ++i)
            ahf[i] = *(const bf16x8_t*)&S[cur][0][(wr + i * 16 + fr) * 32 + sS];
        #pragma unroll
        for (int j = 0; j < 4; ++j)
            bhf[j] = *(const bf16x8_t*)&S[cur][2][(wc + j * 16 + fr) * 32 + sS];
        if (more) {
            issue2(Ah, brow, 0, nxt, kn);
            issue2(Bh, bcol, 2, nxt, kn);
            asm volatile("s_waitcnt vmcnt(6)" ::: "memory");
        } else {
            asm volatile("s_waitcnt vmcnt(2)" ::: "memory");
        }
        __builtin_amdgcn_s_barrier();
        asm volatile("s_waitcnt lgkmcnt(0)" ::: "memory");
        __builtin_amdgcn_sched_barrier(0);
        __builtin_amdgcn_s_setprio(1);
        #pragma unroll
        for (int i = 0; i < 4; ++i)
            #pragma unroll
            for (int j = 0; j < 4; ++j)
                acc[i][j] = __builtin_amdgcn_mfma_f32_16x16x32_bf16(ahf[i], bhf[j], acc[i][j], 0, 0, 0);
        __builtin_amdgcn_s_setprio(0);
        __builtin_amdgcn_s_barrier();

        // ---- phase 1: hl — read Bl(cur); issue G1(t+1); confirm G2(t)
        #pragma unroll
        for (int j = 0; j < 4; ++j)
            blf[j] = *(const bf16x8_t*)&S[cur][3][(wc + j * 16 + fr) * 32 + sS];
        if (more) {
            issue2(Bl, bcol, 3, nxt, kn);
            asm volatile("s_waitcnt vmcnt(6)" ::: "memory");
        } else {
            asm volatile("s_waitcnt vmcnt(0)" ::: "memory");
        }
        __builtin_amdgcn_s_barrier();
        asm volatile("s_waitcnt lgkmcnt(0)" ::: "memory");
        __builtin_amdgcn_sched_barrier(0);
        __builtin_amdgcn_s_setprio(1);
        #pragma unroll
        for (int i = 0; i < 4; ++i)
            #pragma unroll
            for (int j = 0; j < 4; ++j)
                acc[i][j] = __builtin_amdgcn_mfma_f32_16x16x32_bf16(ahf[i], blf[j], acc[i][j], 0, 0, 0);
        __builtin_amdgcn_s_setprio(0);
        __builtin_amdgcn_s_barrier();

        // ---- phase 2: lh — read Al(cur); issue G2(t+1); confirm G0(t+1)
        #pragma unroll
        for (int i = 0; i < 4; ++i)
            alf[i] = *(const bf16x8_t*)&S[cur][1][(wr + i * 16 + fr) * 32 + sS];
        if (more) {
            issue2(Al, brow, 1, nxt, kn);
            asm volatile("s_waitcnt vmcnt(4)" ::: "memory");
        }
        __builtin_amdgcn_s_barrier();
        asm volatile("s_waitcnt lgkmcnt(0)" ::: "memory");
        __builtin_amdgcn_sched_barrier(0);
        __builtin_amdgcn_s_setprio(1);
        #pragma unroll
        for (int i = 0; i < 4; ++i)
            #pragma unroll
            for (int j = 0; j < 4; ++j)
                acc[i][j] = __builtin_amdgcn_mfma_f32_16x16x32_bf16(alf[i], bhf[j], acc[i][j], 0, 0, 0);
        __builtin_amdgcn_s_setprio(0);
        __builtin_amdgcn_s_barrier();
    }

    // ---- epilogue (r9-validated) ----
    if (OMODE == 0) {
        #pragma unroll
        for (int j = 0; j < 4; ++j) {
            int col = bcol + wc + j * 16 + cl;
            #pragma unroll
            for (int i = 0; i < 4; ++i)
                #pragma unroll
                for (int r = 0; r < 4; ++r) {
                    int row = brow + wr + i * 16 + rq + r;
                    float v = acc[i][j][r] + bpre[j];
                    if (RELU) v = fmaxf(v, 0.f);
                    C[(size_t)row * N + col] = v;
                }
        }
    } else {
        // coalesced bounce: wave-private 64x64 f32 view over staging LDS
        float* E = (float*)&S[0][0][0] + w * 4096;   // 16KB per wave
        #pragma unroll
        for (int j = 0; j < 4; ++j) {
            #pragma unroll
            for (int i = 0; i < 4; ++i)
                #pragma unroll
                for (int r = 0; r < 4; ++r) {
                    float v = acc[i][j][r] + bpre[j];
                    if (RELU) v = fmaxf(v, 0.f);
                    E[(i * 16 + rq + r) * 64 + j * 16 + cl] = v;
                }
        }
        __syncthreads();
        const int rr8 = lane >> 3;          // 0..7
        const int c8  = (lane & 7) * 8;     // col base (8 f32 = 32B aligned)
        #pragma unroll
        for (int p = 0; p < 8; ++p) {
            int rl = p * 8 + rr8;
            float4 va = *(float4*)&E[rl * 64 + c8];
            float4 vb = *(float4*)&E[rl * 64 + c8 + 4];
            float v[8] = {va.x, va.y, va.z, va.w, vb.x, vb.y, vb.z, vb.w};
            bf16x8_t hv, lv;
            #pragma unroll
            for (int q = 0; q < 8; ++q) {
                ushort hh = f2bf_rne(v[q]);
                hv[q] = (short)hh;
                lv[q] = (short)f2bf_rne(v[q] - bf2f(hh));
            }
            size_t o = (size_t)(brow + wr + rl) * N + (bcol + wc + c8);
            *(bf16x8_t*)&Ch[o] = hv;
            if (OMODE == 1) *(bf16x8_t*)&Cl[o] = lv;
        }
    }
}

// bijective XCD-chunked swizzle (nwg % 8 == 0 for all our grids)
__device__ __forceinline__ void swz_block(int& brow, int& bcol, int tile) {
    const int nx  = gridDim.x;
    const int lin = blockIdx.y * nx + blockIdx.x;
    const int cpx = (nx * gridDim.y) >> 3;
    const int swz = (lin & 7) * cpx + (lin >> 3);
    brow = (swz / nx) * tile;
    bcol = (swz % nx) * tile;
}

template<bool RELU, int OMODE>
__global__ __launch_bounds__(256) void gemm_mfma(
        const ushort* __restrict__ Ah, const ushort* __restrict__ Al,
        const ushort* __restrict__ Bh, const ushort* __restrict__ Bl,
        const float* __restrict__ bias,
        float* __restrict__ C, ushort* __restrict__ Ch, ushort* __restrict__ Cl,
        int M, int N, int Kd)
{
    int brow, bcol;
    swz_block(brow, bcol, 128);
    gemm_body<RELU, OMODE>(Ah, Al, Bh, Bl, bias, C, Ch, Cl, M, N, Kd, Kd, brow, bcol);
}

// split-K=2: grid.z picks K-window; z=0 carries bias -> C0, z=1 -> C1 (no
// bias). Partial sums combined in add_ln3. fp32 out (OMODE 0) only.
__global__ __launch_bounds__(256) void gemm_splitk2(
        const ushort* __restrict__ Ah, const ushort* __restrict__ Al,
        const ushort* __restrict__ Bh, const ushort* __restrict__ Bl,
        const float* __restrict__ bias,
        float* __restrict__ C0, float* __restrict__ C1,
        int M, int N, int Kd)
{
    int brow, bcol;
    swz_block(brow, bcol, 128);
    const int z = blockIdx.z;
    const int Kh2 = Kd >> 1;
    const int ko  = z * Kh2;
    gemm_body<false, 0>(Ah + ko, Al + ko, Bh + ko, Bl + ko,
                        z == 0 ? bias : nullptr,
                        z == 0 ? C0 : C1, nullptr, nullptr,
                        M, N, Kd, Kh2, brow, bcol);
}

// q/k/v projections fused into one dispatch (grid.z = 3 -> 768 blocks)
struct QkvArgs {
    const ushort* Ah[3]; const ushort* Al[3];
    const ushort* Bh[3]; const ushort* Bl[3];
    const float*  bias[3];
    ushort*       Co[3];
};

__global__ __launch_bounds__(256) void gemm_qkv(QkvArgs qa, int M, int N, int Kd)
{
    int brow, bcol;
    swz_block(brow, bcol, 128);
    const int z = blockIdx.z;
    gemm_body<false, 2>(qa.Ah[z], qa.Al[z], qa.Bh[z], qa.Bl[z], qa.bias[z],
                        nullptr, qa.Co[z], nullptr, M, N, Kd, Kd, brow, bcol);
}

// ---------------------------------------------------------------------------
// MFMA flash attention (validated round 4). 1024 blocks, 4 waves, QBLK=64,
// KVBLK=32; online softmax via 16-lane shfl_xor; output split planes.
// ---------------------------------------------------------------------------
__global__ __launch_bounds__(256) void flash_attn_mfma(
        const ushort* __restrict__ qh, const ushort* __restrict__ kh,
        const ushort* __restrict__ vh,
        ushort* __restrict__ Oh, ushort* __restrict__ Ol)
{
    __shared__ __align__(16) ushort sk[32 * 72];
    __shared__ __align__(16) ushort svt[64 * 40];
    __shared__ __align__(16) ushort pbuf[4][16 * 40];

    const int bid  = blockIdx.x;
    const int slot = bid >> 3;
    const int bh   = (bid & 7) * 8 + (slot >> 4);
    const int qt   = slot & 15;
    const int b    = bh >> 4;
    const int h    = bh & 15;
    const int qb   = qt * 64;

    const int t = threadIdx.x, lane = t & 63, w = t >> 6;
    const int l15 = lane & 15, g = lane >> 4;

    bf16x8_t qf[2];
    {
        size_t qrow = ((size_t)(b * NQ_) + qb + w * 16 + l15) * D_ + h * DH_;
        qf[0] = *(const bf16x8_t*)&qh[qrow + 0  + 8 * g];
        qf[1] = *(const bf16x8_t*)&qh[qrow + 32 + 8 * g];
    }

    f32x4_t acc[4];
    #pragma unroll
    for (int dt = 0; dt < 4; ++dt) acc[dt] = (f32x4_t){0.f, 0.f, 0.f, 0.f};
    float m[4]    = {-INFINITY, -INFINITY, -INFINITY, -INFINITY};
    float lsum[4] = {0.f, 0.f, 0.f, 0.f};

    const int kkv = t >> 3,  kds = (t & 7) * 8;
    const int vkv = t & 31,  vds = (t >> 5) * 8;
    const size_t kvbase = (size_t)(b * NK_) * D_ + h * DH_;

    for (int kt = 0; kt < NK_; kt += 32) {
        __syncthreads();
        {
            bf16x8_t kk = *(const bf16x8_t*)&kh[kvbase + (size_t)(kt + kkv) * D_ + kds];
            *(bf16x8_t*)&sk[kkv * 72 + kds] = kk;
            bf16x8_t vv = *(const bf16x8_t*)&vh[kvbase + (size_t)(kt + vkv) * D_ + vds];
            #pragma unroll
            for (int j = 0; j < 8; ++j)
                svt[(vds + j) * 40 + vkv] = (ushort)vv[j];
        }
        __syncthreads();

        f32x4_t s0 = (f32x4_t){0.f,0.f,0.f,0.f};
        f32x4_t s1 = (f32x4_t){0.f,0.f,0.f,0.f};
        #pragma unroll
        for (int c = 0; c < 2; ++c) {
            bf16x8_t k0 = *(const bf16x8_t*)&sk[(l15     ) * 72 + 32 * c + 8 * g];
            bf16x8_t k1 = *(const bf16x8_t*)&sk[(l15 + 16) * 72 + 32 * c + 8 * g];
            s0 = __builtin_amdgcn_mfma_f32_16x16x32_bf16(qf[c], k0, s0, 0, 0, 0);
            s1 = __builtin_amdgcn_mfma_f32_16x16x32_bf16(qf[c], k1, s1, 0, 0, 0);
        }

        float p0[4], p1[4], corr[4];
        #pragma unroll
        for (int r = 0; r < 4; ++r) {
            float e0 = s0[r] * SCALE_, e1 = s1[r] * SCALE_;
            float tm = fmaxf(e0, e1);
            tm = fmaxf(tm, __shfl_xor(tm, 1, 64));
            tm = fmaxf(tm, __shfl_xor(tm, 2, 64));
            tm = fmaxf(tm, __shfl_xor(tm, 4, 64));
            tm = fmaxf(tm, __shfl_xor(tm, 8, 64));
            float mn = fmaxf(m[r], tm);
            corr[r] = __expf(m[r] - mn);
            p0[r] = __expf(e0 - mn);
            p1[r] = __expf(e1 - mn);
            float ps = p0[r] + p1[r];
            ps += __shfl_xor(ps, 1, 64);
            ps += __shfl_xor(ps, 2, 64);
            ps += __shfl_xor(ps, 4, 64);
            ps += __shfl_xor(ps, 8, 64);
            lsum[r] = lsum[r] * corr[r] + ps;
            m[r] = mn;
        }
        #pragma unroll
        for (int dt = 0; dt < 4; ++dt)
            #pragma unroll
            for (int r = 0; r < 4; ++r)
                acc[dt][r] *= corr[r];

        ushort* pw = &pbuf[w][0];
        #pragma unroll
        for (int r = 0; r < 4; ++r) {
            pw[(4 * g + r) * 40 + l15     ] = f2bf_rne(p0[r]);
            pw[(4 * g + r) * 40 + l15 + 16] = f2bf_rne(p1[r]);
        }
        bf16x8_t pa = *(const bf16x8_t*)&pw[l15 * 40 + 8 * g];

        #pragma unroll
        for (int dt = 0; dt < 4; ++dt) {
            bf16x8_t vf = *(const bf16x8_t*)&svt[(16 * dt + l15) * 40 + 8 * g];
            acc[dt] = __builtin_amdgcn_mfma_f32_16x16x32_bf16(pa, vf, acc[dt], 0, 0, 0);
        }
    }

    float inv[4];
    #pragma unroll
    for (int r = 0; r < 4; ++r) inv[r] = 1.0f / lsum[r];
    #pragma unroll
    for (int dt = 0; dt < 4; ++dt) {
        #pragma unroll
        for (int r = 0; r < 4; ++r) {
            int row = b * NQ_ + qb + w * 16 + 4 * g + r;
            int col = h * DH_ + 16 * dt + l15;
            float v = acc[dt][r] * inv[r];
            ushort hh = f2bf_rne(v);
            Oh[(size_t)row * D_ + col] = hh;
            Ol[(size_t)row * D_ + col] = f2bf_rne(v - bf2f(hh));
        }
    }
}

// ---------------------------------------------------------------------------
// out = LayerNorm(a0 + a1 + r) * g + be. SPLIT: also emit bf16 hi/lo planes.
// (3-input variant fuses split-K partial sum; out may alias a1 — each thread
// reads its own elements before writing them, blocks own disjoint rows.)
// ---------------------------------------------------------------------------
template<bool SPLIT>
__global__ __launch_bounds__(256) void add_ln3(const float* __restrict__ a0,
        const float* __restrict__ a1, const float* __restrict__ r,
        const float* __restrict__ g, const float* __restrict__ be,
        float* __restrict__ out, ushort* __restrict__ oh, ushort* __restrict__ ol)
{
    const int row = blockIdx.x;
    const int t = threadIdx.x;
    float vals[4];
    float s1 = 0.0f, s2 = 0.0f;
    #pragma unroll
    for (int i = 0; i < 4; ++i) {
        int col = t + i * 256;
        size_t o = (size_t)row * D_ + col;
        float vv = a0[o] + a1[o] + r[o];
        vals[i] = vv;
        s1 += vv;
        s2 += vv * vv;
    }
    #pragma unroll
    for (int off = 32; off > 0; off >>= 1) {
        s1 += __shfl_down(s1, off, 64);
        s2 += __shfl_down(s2, off, 64);
    }
    __shared__ float p1[4], p2[4];
    const int wave = t >> 6;
    if ((t & 63) == 0) { p1[wave] = s1; p2[wave] = s2; }
    __syncthreads();
    s1 = p1[0] + p1[1] + p1[2] + p1[3];
    s2 = p2[0] + p2[1] + p2[2] + p2[3];
    const float mean = s1 * (1.0f / D_);
    const float var  = s2 * (1.0f / D_) - mean * mean;
    const float rstd = rsqrtf(var + LN_EPS_);
    #pragma unroll
    for (int i = 0; i < 4; ++i) {
        int col = t + i * 256;
        float v = (vals[i] - mean) * rstd * g[col] + be[col];
        out[(size_t)row * D_ + col] = v;
        if (SPLIT) {
            ushort h = f2bf_rne(v);
            oh[(size_t)row * D_ + col] = h;
            ol[(size_t)row * D_ + col] = f2bf_rne(v - bf2f(h));
        }
    }
}

// ---------------------------------------------------------------------------
// Workspace timeline (MB offsets, 112MB max):
//   Qh 0 Ql 8 Kh 16 Kl 24 | W splits 32..48 | qhp 48 khp 56 vhp 64
//   attn: aOh 72 aOl 80
//   Wo splitk: oprj0@16 (bias), oprj1@56
//   add_ln3<true>: Xf@0 Xh@32 Xl@40
//   W1h@16 W1l@24 ; FFN1 -> Hih@80(32MB) Hil@48(32MB)
//   W2h@16 W2l@24 ; FFN2 splitk: Y0@32 (bias), Y1 = d_out (scratch)
//   add_ln3<false>(Y0, d_out, Xf) -> d_out
// ---------------------------------------------------------------------------
extern "C" void kernel_launch(void* const* d_in, const int* in_sizes, int n_in,
                              void* d_out, int out_size, void* d_ws, size_t ws_size,
                              hipStream_t stream)
{
    const float* Q   = (const float*)d_in[0];
    const float* K   = (const float*)d_in[1];
    const float* Wq  = (const float*)d_in[2];
    const float* bq  = (const float*)d_in[3];
    const float* Wk  = (const float*)d_in[4];
    const float* bk  = (const float*)d_in[5];
    const float* Wv  = (const float*)d_in[6];
    const float* bv  = (const float*)d_in[7];
    const float* Wo  = (const float*)d_in[8];
    const float* bo  = (const float*)d_in[9];
    const float* W1  = (const float*)d_in[10];
    const float* b1  = (const float*)d_in[11];
    const float* W2  = (const float*)d_in[12];
    const float* b2  = (const float*)d_in[13];
    const float* g0  = (const float*)d_in[14];
    const float* be0 = (const float*)d_in[15];
    const float* g1  = (const float*)d_in[16];
    const float* be1 = (const float*)d_in[17];

    unsigned char* Wb = (unsigned char*)d_ws;
    const size_t MBy = 1ull << 20;

    ushort* Qh   = (ushort*)(Wb +  0 * MBy);
    ushort* Ql   = (ushort*)(Wb +  8 * MBy);
    ushort* Kh   = (ushort*)(Wb + 16 * MBy);
    ushort* Kl   = (ushort*)(Wb + 24 * MBy);
    ushort* Wqh  = (ushort*)(Wb + 32 * MBy);
    ushort* Wql  = (ushort*)(Wb + 34 * MBy);
    ushort* Wkh  = (ushort*)(Wb + 36 * MBy);
    ushort* Wkl  = (ushort*)(Wb + 38 * MBy);
    ushort* Wvh  = (ushort*)(Wb + 40 * MBy);
    ushort* Wvl  = (ushort*)(Wb + 42 * MBy);
    ushort* Woh  = (ushort*)(Wb + 44 * MBy);
    ushort* Wol  = (ushort*)(Wb + 46 * MBy);
    ushort* qhp  = (ushort*)(Wb + 48 * MBy);
    ushort* khp  = (ushort*)(Wb + 56 * MBy);
    ushort* vhp  = (ushort*)(Wb + 64 * MBy);
    ushort* aOh  = (ushort*)(Wb + 72 * MBy);
    ushort* aOl  = (ushort*)(Wb + 80 * MBy);

    float*  oprj0 = (float*)(Wb + 16 * MBy);
    float*  oprj1 = (float*)(Wb + 56 * MBy);
    float*  Xf    = (float*)(Wb +  0 * MBy);
    ushort* Xh    = (ushort*)(Wb + 32 * MBy);
    ushort* Xl    = (ushort*)(Wb + 40 * MBy);
    ushort* W1h   = (ushort*)(Wb + 16 * MBy);
    ushort* W1l   = (ushort*)(Wb + 24 * MBy);
    ushort* Hih   = (ushort*)(Wb + 80 * MBy);   // 32MB: 80-112
    ushort* Hil   = (ushort*)(Wb + 48 * MBy);   // 32MB: 48-80
    ushort* W2h   = (ushort*)(Wb + 16 * MBy);
    ushort* W2l   = (ushort*)(Wb + 24 * MBy);
    float*  Y0    = (float*)(Wb + 32 * MBy);
    float*  Y1    = (float*)d_out;              // scratch until final LN

    const int M = B_ * NQ_;
    const int n4act = M * D_ / 4;
    dim3 blk(256);
    dim3 gQKV(D_ / 128, M / 128, 3);
    dim3 gSK(D_ / 128, M / 128, 2);
    dim3 gF(DFF_ / 128, M / 128);

    split_rows<<<n4act / 256, blk, 0, stream>>>(Q, Qh, Ql, n4act);
    split_rows<<<n4act / 256, blk, 0, stream>>>(K, Kh, Kl, n4act);
    split_tr<<<dim3(D_/32, D_/32), blk, 0, stream>>>(Wq, Wqh, Wql, D_, D_);
    split_tr<<<dim3(D_/32, D_/32), blk, 0, stream>>>(Wk, Wkh, Wkl, D_, D_);
    split_tr<<<dim3(D_/32, D_/32), blk, 0, stream>>>(Wv, Wvh, Wvl, D_, D_);
    split_tr<<<dim3(D_/32, D_/32), blk, 0, stream>>>(Wo, Woh, Wol, D_, D_);

    QkvArgs qa;
    qa.Ah[0] = Qh;  qa.Al[0] = Ql;  qa.Bh[0] = Wqh; qa.Bl[0] = Wql; qa.bias[0] = bq; qa.Co[0] = qhp;
    qa.Ah[1] = Kh;  qa.Al[1] = Kl;  qa.Bh[1] = Wkh; qa.Bl[1] = Wkl; qa.bias[1] = bk; qa.Co[1] = khp;
    qa.Ah[2] = Kh;  qa.Al[2] = Kl;  qa.Bh[2] = Wvh; qa.Bl[2] = Wvl; qa.bias[2] = bv; qa.Co[2] = vhp;
    gemm_qkv<<<gQKV, blk, 0, stream>>>(qa, M, D_, D_);

    flash_attn_mfma<<<dim3(1024), blk, 0, stream>>>(qhp, khp, vhp, aOh, aOl);

    // output projection, split-K=2 (2 blocks/CU) + fused 3-input LN
    gemm_splitk2<<<gSK, blk, 0, stream>>>(aOh, aOl, Woh, Wol, bo, oprj0, oprj1, M, D_, D_);
    add_ln3<true><<<M, blk, 0, stream>>>(oprj0, oprj1, Q, g0, be0, Xf, Xh, Xl);

    split_tr<<<dim3(DFF_/32, D_/32), blk, 0, stream>>>(W1, W1h, W1l, D_, DFF_);
    gemm_mfma<true,1><<<gF, blk, 0, stream>>>(Xh, Xl, W1h, W1l, b1, nullptr, Hih, Hil, M, DFF_, D_);
    split_tr<<<dim3(D_/32, DFF_/32), blk, 0, stream>>>(W2, W2h, W2l, DFF_, D_);

    // FFN2, split-K=2; Y1 uses d_out as scratch (dead until final LN)
    gemm_splitk2<<<gSK, blk, 0, stream>>>(Hih, Hil, W2h, W2l, b2, Y0, Y1, M, D_, DFF_);
    add_ln3<false><<<M, blk, 0, stream>>>(Y0, Y1, Xf, g1, be1, (float*)d_out, nullptr, nullptr);
}

// Round 12
// 413.282 us; speedup vs baseline: 1.3393x; 1.0963x over previous
//
#include <hip/hip_runtime.h>
#include <math.h>

#define B_   4
#define NQ_  1024
#define NK_  1024
#define D_   1024
#define H_   16
#define DH_  64
#define DFF_ 4096
#define SCALE_ (1.0f/32.0f)   // 1/sqrt(D)
#define LN_EPS_ 1e-5f

typedef __attribute__((ext_vector_type(8))) short bf16x8_t;  // 8 bf16 = 4 VGPR
typedef __attribute__((ext_vector_type(4))) float f32x4_t;

__device__ __forceinline__ ushort f2bf_rne(float x) {
    unsigned u = __float_as_uint(x);
    unsigned r = (u + 0x7FFFu + ((u >> 16) & 1u)) >> 16;
    return (ushort)r;
}
__device__ __forceinline__ float bf2f(ushort h) {
    return __uint_as_float(((unsigned)h) << 16);
}

// async global->LDS, 16B per lane. LDS dest = wave-uniform base + lane*16.
__device__ __forceinline__ void gl_lds16(const ushort* g, ushort* l) {
    __builtin_amdgcn_global_load_lds(
        (const __attribute__((address_space(1))) unsigned int*)g,
        (__attribute__((address_space(3))) unsigned int*)l, 16, 0, 0);
}

// ---------------------------------------------------------------------------
// fp32 -> (hi,lo) bf16 planes.
// ---------------------------------------------------------------------------
__global__ __launch_bounds__(256) void split_rows(const float* __restrict__ src,
        ushort* __restrict__ hi, ushort* __restrict__ lo, int n4)
{
    int i = blockIdx.x * 256 + threadIdx.x;
    if (i >= n4) return;
    float4 v = ((const float4*)src)[i];
    ushort4 h, l;
    h.x = f2bf_rne(v.x); l.x = f2bf_rne(v.x - bf2f(h.x));
    h.y = f2bf_rne(v.y); l.y = f2bf_rne(v.y - bf2f(h.y));
    h.z = f2bf_rne(v.z); l.z = f2bf_rne(v.z - bf2f(h.z));
    h.w = f2bf_rne(v.w); l.w = f2bf_rne(v.w - bf2f(h.w));
    ((ushort4*)hi)[i] = h;
    ((ushort4*)lo)[i] = l;
}

// ---------------------------------------------------------------------------
// Weight split + transpose: W[K][N] fp32 -> planes Wt[N][K] bf16.
// ---------------------------------------------------------------------------
__global__ __launch_bounds__(256) void split_tr(const float* __restrict__ Wsrc,
        ushort* __restrict__ th, ushort* __restrict__ tl, int K, int N)
{
    __shared__ float tile[32][33];
    const int nb = blockIdx.x * 32, kb = blockIdx.y * 32;
    const int t = threadIdx.x;
    {
        int r = t >> 3, c4 = (t & 7) * 4;
        float4 v = *(const float4*)&Wsrc[(size_t)(kb + r) * N + nb + c4];
        tile[r][c4 + 0] = v.x; tile[r][c4 + 1] = v.y;
        tile[r][c4 + 2] = v.z; tile[r][c4 + 3] = v.w;
    }
    __syncthreads();
    {
        int n = t >> 3, k4 = (t & 7) * 4;
        float a0 = tile[k4 + 0][n], a1 = tile[k4 + 1][n];
        float a2 = tile[k4 + 2][n], a3 = tile[k4 + 3][n];
        ushort4 h, l;
        h.x = f2bf_rne(a0); l.x = f2bf_rne(a0 - bf2f(h.x));
        h.y = f2bf_rne(a1); l.y = f2bf_rne(a1 - bf2f(h.y));
        h.z = f2bf_rne(a2); l.z = f2bf_rne(a2 - bf2f(h.z));
        h.w = f2bf_rne(a3); l.w = f2bf_rne(a3 - bf2f(h.w));
        size_t o = (size_t)(nb + n) * K + kb + k4;
        *(ushort4*)&th[o] = h;
        *(ushort4*)&tl[o] = l;
    }
}

// ---------------------------------------------------------------------------
// MFMA GEMM body (r10-validated counted-vmcnt fine-phase pipeline).
// Kd = row stride; Klen = K extent of this block's work (split-K window).
// bias == nullptr -> no bias. OMODE: 0 fp32, 1 split planes, 2 hi-only.
// ---------------------------------------------------------------------------
template<bool RELU, int OMODE>
__device__ __forceinline__ void gemm_body(
        const ushort* __restrict__ Ah, const ushort* __restrict__ Al,
        const ushort* __restrict__ Bh, const ushort* __restrict__ Bl,
        const float* __restrict__ bias,
        float* __restrict__ C, ushort* __restrict__ Ch, ushort* __restrict__ Cl,
        int M, int N, int Kd, int Klen, int brow, int bcol)
{
    __shared__ __align__(16) ushort S[2][4][128 * 32];   // 64KB dbuf

    const int t    = threadIdx.x;
    const int lane = t & 63;
    const int w    = t >> 6;
    const int wr   = (w >> 1) * 64;
    const int wc   = (w & 1) * 64;
    const int fr   = lane & 15;
    const int g    = lane >> 4;
    const int sS   = ((g ^ ((fr >> 1) & 3)) << 3);
    const int cl   = lane & 15;
    const int rq   = (lane >> 4) * 4;

    // bias preload (issued before staging so it drains with prologue G0)
    float bpre[4];
    #pragma unroll
    for (int j = 0; j < 4; ++j)
        bpre[j] = bias ? bias[bcol + wc + j * 16 + cl] : 0.f;

    f32x4_t acc[4][4];
    #pragma unroll
    for (int i = 0; i < 4; ++i)
        #pragma unroll
        for (int j = 0; j < 4; ++j)
            acc[i][j] = (f32x4_t){0.f, 0.f, 0.f, 0.f};

    const int lrow  = lane >> 2;
    const int lslot = ((lane & 3) ^ ((lane >> 3) & 3)) << 3;
    const int c0    = w * 2;   // this wave's 2 chunks (16 rows each) per plane

    auto issue2 = [&](const ushort* gpp, int rb, int pl, int buf, int k0) {
        #pragma unroll
        for (int ii = 0; ii < 2; ++ii) {
            int c = c0 + ii;
            gl_lds16(gpp + (size_t)(rb + c * 16 + lrow) * Kd + k0 + lslot,
                     &S[buf][pl][c * 512]);
        }
    };

    bf16x8_t ahf[4], bhf[4], blf[4], alf[4];

    // prologue: tile 0 into buf 0, issue order G0=[Ah,Bh], G1=[Bl], G2=[Al]
    issue2(Ah, brow, 0, 0, 0);
    issue2(Bh, bcol, 2, 0, 0);
    issue2(Bl, bcol, 3, 0, 0);
    issue2(Al, brow, 1, 0, 0);
    asm volatile("s_waitcnt vmcnt(4)" ::: "memory");   // G0(tile0) done
    __builtin_amdgcn_s_barrier();

    const int NT = Klen >> 5;
    for (int tt = 0; tt < NT; ++tt) {
        const int cur = tt & 1, nxt = cur ^ 1;
        const int kn  = (tt + 1) << 5;
        const bool more = (tt + 1 < NT);

        // ---- phase 0: hh — read Ah,Bh(cur); issue G0(t+1); confirm G1(t)
        #pragma unroll
        for (int i = 0; i < 4; ++i)
            ahf[i] = *(const bf16x8_t*)&S[cur][0][(wr + i * 16 + fr) * 32 + sS];
        #pragma unroll
        for (int j = 0; j < 4; ++j)
            bhf[j] = *(const bf16x8_t*)&S[cur][2][(wc + j * 16 + fr) * 32 + sS];
        if (more) {
            issue2(Ah, brow, 0, nxt, kn);
            issue2(Bh, bcol, 2, nxt, kn);
            asm volatile("s_waitcnt vmcnt(6)" ::: "memory");
        } else {
            asm volatile("s_waitcnt vmcnt(2)" ::: "memory");
        }
        __builtin_amdgcn_s_barrier();
        asm volatile("s_waitcnt lgkmcnt(0)" ::: "memory");
        __builtin_amdgcn_sched_barrier(0);
        __builtin_amdgcn_s_setprio(1);
        #pragma unroll
        for (int i = 0; i < 4; ++i)
            #pragma unroll
            for (int j = 0; j < 4; ++j)
                acc[i][j] = __builtin_amdgcn_mfma_f32_16x16x32_bf16(ahf[i], bhf[j], acc[i][j], 0, 0, 0);
        __builtin_amdgcn_s_setprio(0);
        __builtin_amdgcn_s_barrier();

        // ---- phase 1: hl — read Bl(cur); issue G1(t+1); confirm G2(t)
        #pragma unroll
        for (int j = 0; j < 4; ++j)
            blf[j] = *(const bf16x8_t*)&S[cur][3][(wc + j * 16 + fr) * 32 + sS];
        if (more) {
            issue2(Bl, bcol, 3, nxt, kn);
            asm volatile("s_waitcnt vmcnt(6)" ::: "memory");
        } else {
            asm volatile("s_waitcnt vmcnt(0)" ::: "memory");
        }
        __builtin_amdgcn_s_barrier();
        asm volatile("s_waitcnt lgkmcnt(0)" ::: "memory");
        __builtin_amdgcn_sched_barrier(0);
        __builtin_amdgcn_s_setprio(1);
        #pragma unroll
        for (int i = 0; i < 4; ++i)
            #pragma unroll
            for (int j = 0; j < 4; ++j)
                acc[i][j] = __builtin_amdgcn_mfma_f32_16x16x32_bf16(ahf[i], blf[j], acc[i][j], 0, 0, 0);
        __builtin_amdgcn_s_setprio(0);
        __builtin_amdgcn_s_barrier();

        // ---- phase 2: lh — read Al(cur); issue G2(t+1); confirm G0(t+1)
        #pragma unroll
        for (int i = 0; i < 4; ++i)
            alf[i] = *(const bf16x8_t*)&S[cur][1][(wr + i * 16 + fr) * 32 + sS];
        if (more) {
            issue2(Al, brow, 1, nxt, kn);
            asm volatile("s_waitcnt vmcnt(4)" ::: "memory");
        }
        __builtin_amdgcn_s_barrier();
        asm volatile("s_waitcnt lgkmcnt(0)" ::: "memory");
        __builtin_amdgcn_sched_barrier(0);
        __builtin_amdgcn_s_setprio(1);
        #pragma unroll
        for (int i = 0; i < 4; ++i)
            #pragma unroll
            for (int j = 0; j < 4; ++j)
                acc[i][j] = __builtin_amdgcn_mfma_f32_16x16x32_bf16(alf[i], bhf[j], acc[i][j], 0, 0, 0);
        __builtin_amdgcn_s_setprio(0);
        __builtin_amdgcn_s_barrier();
    }

    // ---- epilogue (r9-validated) ----
    if (OMODE == 0) {
        #pragma unroll
        for (int j = 0; j < 4; ++j) {
            int col = bcol + wc + j * 16 + cl;
            #pragma unroll
            for (int i = 0; i < 4; ++i)
                #pragma unroll
                for (int r = 0; r < 4; ++r) {
                    int row = brow + wr + i * 16 + rq + r;
                    float v = acc[i][j][r] + bpre[j];
                    if (RELU) v = fmaxf(v, 0.f);
                    C[(size_t)row * N + col] = v;
                }
        }
    } else {
        // coalesced bounce: wave-private 64x64 f32 view over staging LDS
        float* E = (float*)&S[0][0][0] + w * 4096;   // 16KB per wave
        #pragma unroll
        for (int j = 0; j < 4; ++j) {
            #pragma unroll
            for (int i = 0; i < 4; ++i)
                #pragma unroll
                for (int r = 0; r < 4; ++r) {
                    float v = acc[i][j][r] + bpre[j];
                    if (RELU) v = fmaxf(v, 0.f);
                    E[(i * 16 + rq + r) * 64 + j * 16 + cl] = v;
                }
        }
        __syncthreads();
        const int rr8 = lane >> 3;          // 0..7
        const int c8  = (lane & 7) * 8;     // col base (8 f32 = 32B aligned)
        #pragma unroll
        for (int p = 0; p < 8; ++p) {
            int rl = p * 8 + rr8;
            float4 va = *(float4*)&E[rl * 64 + c8];
            float4 vb = *(float4*)&E[rl * 64 + c8 + 4];
            float v[8] = {va.x, va.y, va.z, va.w, vb.x, vb.y, vb.z, vb.w};
            bf16x8_t hv, lv;
            #pragma unroll
            for (int q = 0; q < 8; ++q) {
                ushort hh = f2bf_rne(v[q]);
                hv[q] = (short)hh;
                lv[q] = (short)f2bf_rne(v[q] - bf2f(hh));
            }
            size_t o = (size_t)(brow + wr + rl) * N + (bcol + wc + c8);
            *(bf16x8_t*)&Ch[o] = hv;
            if (OMODE == 1) *(bf16x8_t*)&Cl[o] = lv;
        }
    }
}

// bijective XCD-chunked swizzle (nwg % 8 == 0 for all our grids)
__device__ __forceinline__ void swz_block(int& brow, int& bcol, int tile) {
    const int nx  = gridDim.x;
    const int lin = blockIdx.y * nx + blockIdx.x;
    const int cpx = (nx * gridDim.y) >> 3;
    const int swz = (lin & 7) * cpx + (lin >> 3);
    brow = (swz / nx) * tile;
    bcol = (swz % nx) * tile;
}

template<bool RELU, int OMODE>
__global__ __launch_bounds__(256) void gemm_mfma(
        const ushort* __restrict__ Ah, const ushort* __restrict__ Al,
        const ushort* __restrict__ Bh, const ushort* __restrict__ Bl,
        const float* __restrict__ bias,
        float* __restrict__ C, ushort* __restrict__ Ch, ushort* __restrict__ Cl,
        int M, int N, int Kd)
{
    int brow, bcol;
    swz_block(brow, bcol, 128);
    gemm_body<RELU, OMODE>(Ah, Al, Bh, Bl, bias, C, Ch, Cl, M, N, Kd, Kd, brow, bcol);
}

// split-K=2: grid.z picks K-window; z=0 carries bias -> C0, z=1 -> C1 (no
// bias). Partial sums combined in add_ln3. fp32 out (OMODE 0) only.
__global__ __launch_bounds__(256) void gemm_splitk2(
        const ushort* __restrict__ Ah, const ushort* __restrict__ Al,
        const ushort* __restrict__ Bh, const ushort* __restrict__ Bl,
        const float* __restrict__ bias,
        float* __restrict__ C0, float* __restrict__ C1,
        int M, int N, int Kd)
{
    int brow, bcol;
    swz_block(brow, bcol, 128);
    const int z = blockIdx.z;
    const int Kh2 = Kd >> 1;
    const int ko  = z * Kh2;
    gemm_body<false, 0>(Ah + ko, Al + ko, Bh + ko, Bl + ko,
                        z == 0 ? bias : nullptr,
                        z == 0 ? C0 : C1, nullptr, nullptr,
                        M, N, Kd, Kh2, brow, bcol);
}

// q/k/v projections fused into one dispatch (grid.z = 3 -> 768 blocks)
struct QkvArgs {
    const ushort* Ah[3]; const ushort* Al[3];
    const ushort* Bh[3]; const ushort* Bl[3];
    const float*  bias[3];
    ushort*       Co[3];
};

__global__ __launch_bounds__(256) void gemm_qkv(QkvArgs qa, int M, int N, int Kd)
{
    int brow, bcol;
    swz_block(brow, bcol, 128);
    const int z = blockIdx.z;
    gemm_body<false, 2>(qa.Ah[z], qa.Al[z], qa.Bh[z], qa.Bl[z], qa.bias[z],
                        nullptr, qa.Co[z], nullptr, M, N, Kd, Kd, brow, bcol);
}

// ---------------------------------------------------------------------------
// MFMA flash attention v2 (r12): swapped operands.
//   S^T = mfma(K, Q): lane (g,l15) holds S[kv=4g+r(+16)][q=l15] -> softmax
//   state (m,l) is a per-lane SCALAR for q=l15; row-reduce = reg-max + 2
//   shfl_xor (16,32) instead of 32 shfls. PV swapped: O^T = mfma(V^T, P),
//   accumulator cols share the same q=l15 -> corr rescale is lane-local.
//   T14 staging: K/V tile t+1 global-loaded into regs right after the stage
//   barrier, consumed at next tile's ds_write (latency hidden under compute).
//   Epilogue: O^T -> O via per-wave LDS bounce, coalesced 16B split stores.
// ---------------------------------------------------------------------------
__global__ __launch_bounds__(256) void flash_attn_mfma(
        const ushort* __restrict__ qh, const ushort* __restrict__ kh,
        const ushort* __restrict__ vh,
        ushort* __restrict__ Oh, ushort* __restrict__ Ol)
{
    __shared__ __align__(16) ushort SMEM[8192];   // 16KB, carved below
    ushort* sk  = SMEM;           // [32][72]  K tile (2304 ushorts)
    ushort* svt = SMEM + 2304;    // [64][40]  V^T tile (2560)
    ushort* pw0 = SMEM + 4864;    // [4][16][40] per-wave P (2560)

    const int bid  = blockIdx.x;
    const int slot = bid >> 3;
    const int bh   = (bid & 7) * 8 + (slot >> 4);
    const int qt   = slot & 15;
    const int b    = bh >> 4;
    const int h    = bh & 15;
    const int qb   = qt * 64;

    const int t = threadIdx.x, lane = t & 63, w = t >> 6;
    const int l15 = lane & 15, g = lane >> 4;

    bf16x8_t qf[2];
    {
        size_t qrow = ((size_t)(b * NQ_) + qb + w * 16 + l15) * D_ + h * DH_;
        qf[0] = *(const bf16x8_t*)&qh[qrow + 0  + 8 * g];
        qf[1] = *(const bf16x8_t*)&qh[qrow + 32 + 8 * g];
    }

    f32x4_t acc[4];   // O^T[d = 16*dt + 4g + r][q = l15]
    #pragma unroll
    for (int dt = 0; dt < 4; ++dt) acc[dt] = (f32x4_t){0.f, 0.f, 0.f, 0.f};
    float m = -INFINITY, l = 0.0f;

    const int kkv = t >> 3,  kds = (t & 7) * 8;
    const int vkv = t & 31,  vds = (t >> 5) * 8;
    const size_t kvbase = (size_t)(b * NK_) * D_ + h * DH_;

    // T14: preload tile 0 into regs
    bf16x8_t kreg = *(const bf16x8_t*)&kh[kvbase + (size_t)kkv * D_ + kds];
    bf16x8_t vreg = *(const bf16x8_t*)&vh[kvbase + (size_t)vkv * D_ + vds];

    ushort* pw = pw0 + w * 640;

    for (int kt = 0; kt < NK_; kt += 32) {
        __syncthreads();                        // prior tile's readers done
        *(bf16x8_t*)&sk[kkv * 72 + kds] = kreg;
        #pragma unroll
        for (int j = 0; j < 8; ++j)
            svt[(vds + j) * 40 + vkv] = (ushort)vreg[j];
        __syncthreads();                        // staged tile visible
        if (kt + 32 < NK_) {                    // prefetch t+1 (hides under compute)
            kreg = *(const bf16x8_t*)&kh[kvbase + (size_t)(kt + 32 + kkv) * D_ + kds];
            vreg = *(const bf16x8_t*)&vh[kvbase + (size_t)(kt + 32 + vkv) * D_ + vds];
        }

        // QK^T swapped: A = K rows (kv), B = Q rows (q) -> S^T[kv][q]
        f32x4_t s0 = (f32x4_t){0.f,0.f,0.f,0.f};
        f32x4_t s1 = (f32x4_t){0.f,0.f,0.f,0.f};
        #pragma unroll
        for (int c = 0; c < 2; ++c) {
            bf16x8_t k0 = *(const bf16x8_t*)&sk[(l15     ) * 72 + 32 * c + 8 * g];
            bf16x8_t k1 = *(const bf16x8_t*)&sk[(l15 + 16) * 72 + 32 * c + 8 * g];
            s0 = __builtin_amdgcn_mfma_f32_16x16x32_bf16(k0, qf[c], s0, 0, 0, 0);
            s1 = __builtin_amdgcn_mfma_f32_16x16x32_bf16(k1, qf[c], s1, 0, 0, 0);
        }

        // per-lane online softmax (q = l15): reg-max + 2 shfl, reg-sum + 2 shfl
        float e0[4], e1[4];
        #pragma unroll
        for (int r = 0; r < 4; ++r) { e0[r] = s0[r] * SCALE_; e1[r] = s1[r] * SCALE_; }
        float tmax = fmaxf(fmaxf(fmaxf(e0[0], e0[1]), fmaxf(e0[2], e0[3])),
                           fmaxf(fmaxf(e1[0], e1[1]), fmaxf(e1[2], e1[3])));
        tmax = fmaxf(tmax, __shfl_xor(tmax, 16, 64));
        tmax = fmaxf(tmax, __shfl_xor(tmax, 32, 64));
        float mn   = fmaxf(m, tmax);
        float corr = __expf(m - mn);
        float p0[4], p1[4];
        float ps = 0.f;
        #pragma unroll
        for (int r = 0; r < 4; ++r) {
            p0[r] = __expf(e0[r] - mn);
            p1[r] = __expf(e1[r] - mn);
            ps += p0[r] + p1[r];
        }
        ps += __shfl_xor(ps, 16, 64);
        ps += __shfl_xor(ps, 32, 64);
        l = l * corr + ps;
        m = mn;
        #pragma unroll
        for (int dt = 0; dt < 4; ++dt)
            #pragma unroll
            for (int r = 0; r < 4; ++r)
                acc[dt][r] *= corr;

        // P -> per-wave LDS, packed b64 writes; read back as PV B-frag
        ushort4 pk0, pk1;
        pk0.x = f2bf_rne(p0[0]); pk0.y = f2bf_rne(p0[1]);
        pk0.z = f2bf_rne(p0[2]); pk0.w = f2bf_rne(p0[3]);
        pk1.x = f2bf_rne(p1[0]); pk1.y = f2bf_rne(p1[1]);
        pk1.z = f2bf_rne(p1[2]); pk1.w = f2bf_rne(p1[3]);
        *(ushort4*)&pw[l15 * 40 + 4 * g]      = pk0;   // kv 4g..4g+3
        *(ushort4*)&pw[l15 * 40 + 16 + 4 * g] = pk1;   // kv 16+4g..
        bf16x8_t pa = *(const bf16x8_t*)&pw[l15 * 40 + 8 * g];

        // PV swapped: O^T[d][q] += V^T[d][kv] * P[q][kv]
        #pragma unroll
        for (int dt = 0; dt < 4; ++dt) {
            bf16x8_t vf = *(const bf16x8_t*)&svt[(16 * dt + l15) * 40 + 8 * g];
            acc[dt] = __builtin_amdgcn_mfma_f32_16x16x32_bf16(vf, pa, acc[dt], 0, 0, 0);
        }
    }

    // epilogue: O^T -> O via per-wave LDS bounce, coalesced split-plane stores
    __syncthreads();                     // all waves done with SMEM (incl. pbuf)
    float invl = 1.0f / l;
    float* Ew = (float*)SMEM + w * 1024;   // per-wave [64 d][16 q] f32 (4KB)
    #pragma unroll
    for (int dt = 0; dt < 4; ++dt)
        #pragma unroll
        for (int r = 0; r < 4; ++r)
            Ew[(16 * dt + 4 * g + r) * 16 + l15] = acc[dt][r] * invl;
    // same-wave write->read: compiler inserts lgkmcnt; per-wave area, no barrier
    const int ql = lane >> 2;            // 0..15 q within wave
    const int dc = (lane & 3) * 16;      // 16-col d chunk
    float ov[16];
    #pragma unroll
    for (int j = 0; j < 16; ++j) ov[j] = Ew[(dc + j) * 16 + ql];
    bf16x8_t hv0, hv1, lv0, lv1;
    #pragma unroll
    for (int j = 0; j < 8; ++j) {
        ushort ha = f2bf_rne(ov[j]);
        ushort hb = f2bf_rne(ov[8 + j]);
        hv0[j] = (short)ha; lv0[j] = (short)f2bf_rne(ov[j] - bf2f(ha));
        hv1[j] = (short)hb; lv1[j] = (short)f2bf_rne(ov[8 + j] - bf2f(hb));
    }
    size_t orow = ((size_t)(b * NQ_) + qb + w * 16 + ql) * D_ + h * DH_ + dc;
    *(bf16x8_t*)&Oh[orow]     = hv0;
    *(bf16x8_t*)&Oh[orow + 8] = hv1;
    *(bf16x8_t*)&Ol[orow]     = lv0;
    *(bf16x8_t*)&Ol[orow + 8] = lv1;
}

// ---------------------------------------------------------------------------
// out = LayerNorm(a0 + a1 + r) * g + be. SPLIT: also emit bf16 hi/lo planes.
// (3-input variant fuses split-K partial sum; out may alias a1 — each thread
// reads its own elements before writing them, blocks own disjoint rows.)
// ---------------------------------------------------------------------------
template<bool SPLIT>
__global__ __launch_bounds__(256) void add_ln3(const float* __restrict__ a0,
        const float* __restrict__ a1, const float* __restrict__ r,
        const float* __restrict__ g, const float* __restrict__ be,
        float* __restrict__ out, ushort* __restrict__ oh, ushort* __restrict__ ol)
{
    const int row = blockIdx.x;
    const int t = threadIdx.x;
    float vals[4];
    float s1 = 0.0f, s2 = 0.0f;
    #pragma unroll
    for (int i = 0; i < 4; ++i) {
        int col = t + i * 256;
        size_t o = (size_t)row * D_ + col;
        float vv = a0[o] + a1[o] + r[o];
        vals[i] = vv;
        s1 += vv;
        s2 += vv * vv;
    }
    #pragma unroll
    for (int off = 32; off > 0; off >>= 1) {
        s1 += __shfl_down(s1, off, 64);
        s2 += __shfl_down(s2, off, 64);
    }
    __shared__ float p1[4], p2[4];
    const int wave = t >> 6;
    if ((t & 63) == 0) { p1[wave] = s1; p2[wave] = s2; }
    __syncthreads();
    s1 = p1[0] + p1[1] + p1[2] + p1[3];
    s2 = p2[0] + p2[1] + p2[2] + p2[3];
    const float mean = s1 * (1.0f / D_);
    const float var  = s2 * (1.0f / D_) - mean * mean;
    const float rstd = rsqrtf(var + LN_EPS_);
    #pragma unroll
    for (int i = 0; i < 4; ++i) {
        int col = t + i * 256;
        float v = (vals[i] - mean) * rstd * g[col] + be[col];
        out[(size_t)row * D_ + col] = v;
        if (SPLIT) {
            ushort h = f2bf_rne(v);
            oh[(size_t)row * D_ + col] = h;
            ol[(size_t)row * D_ + col] = f2bf_rne(v - bf2f(h));
        }
    }
}

// ---------------------------------------------------------------------------
// Workspace timeline (MB offsets, 112MB max):
//   Qh 0 Ql 8 Kh 16 Kl 24 | W splits 32..48 | qhp 48 khp 56 vhp 64
//   attn: aOh 72 aOl 80
//   Wo splitk: oprj0@16 (bias), oprj1@56
//   add_ln3<true>: Xf@0 Xh@32 Xl@40
//   W1h@16 W1l@24 ; FFN1 -> Hih@80(32MB) Hil@48(32MB)
//   W2h@16 W2l@24 ; FFN2 splitk: Y0@32 (bias), Y1 = d_out (scratch)
//   add_ln3<false>(Y0, d_out, Xf) -> d_out
// ---------------------------------------------------------------------------
extern "C" void kernel_launch(void* const* d_in, const int* in_sizes, int n_in,
                              void* d_out, int out_size, void* d_ws, size_t ws_size,
                              hipStream_t stream)
{
    const float* Q   = (const float*)d_in[0];
    const float* K   = (const float*)d_in[1];
    const float* Wq  = (const float*)d_in[2];
    const float* bq  = (const float*)d_in[3];
    const float* Wk  = (const float*)d_in[4];
    const float* bk  = (const float*)d_in[5];
    const float* Wv  = (const float*)d_in[6];
    const float* bv  = (const float*)d_in[7];
    const float* Wo  = (const float*)d_in[8];
    const float* bo  = (const float*)d_in[9];
    const float* W1  = (const float*)d_in[10];
    const float* b1  = (const float*)d_in[11];
    const float* W2  = (const float*)d_in[12];
    const float* b2  = (const float*)d_in[13];
    const float* g0  = (const float*)d_in[14];
    const float* be0 = (const float*)d_in[15];
    const float* g1  = (const float*)d_in[16];
    const float* be1 = (const float*)d_in[17];

    unsigned char* Wb = (unsigned char*)d_ws;
    const size_t MBy = 1ull << 20;

    ushort* Qh   = (ushort*)(Wb +  0 * MBy);
    ushort* Ql   = (ushort*)(Wb +  8 * MBy);
    ushort* Kh   = (ushort*)(Wb + 16 * MBy);
    ushort* Kl   = (ushort*)(Wb + 24 * MBy);
    ushort* Wqh  = (ushort*)(Wb + 32 * MBy);
    ushort* Wql  = (ushort*)(Wb + 34 * MBy);
    ushort* Wkh  = (ushort*)(Wb + 36 * MBy);
    ushort* Wkl  = (ushort*)(Wb + 38 * MBy);
    ushort* Wvh  = (ushort*)(Wb + 40 * MBy);
    ushort* Wvl  = (ushort*)(Wb + 42 * MBy);
    ushort* Woh  = (ushort*)(Wb + 44 * MBy);
    ushort* Wol  = (ushort*)(Wb + 46 * MBy);
    ushort* qhp  = (ushort*)(Wb + 48 * MBy);
    ushort* khp  = (ushort*)(Wb + 56 * MBy);
    ushort* vhp  = (ushort*)(Wb + 64 * MBy);
    ushort* aOh  = (ushort*)(Wb + 72 * MBy);
    ushort* aOl  = (ushort*)(Wb + 80 * MBy);

    float*  oprj0 = (float*)(Wb + 16 * MBy);
    float*  oprj1 = (float*)(Wb + 56 * MBy);
    float*  Xf    = (float*)(Wb +  0 * MBy);
    ushort* Xh    = (ushort*)(Wb + 32 * MBy);
    ushort* Xl    = (ushort*)(Wb + 40 * MBy);
    ushort* W1h   = (ushort*)(Wb + 16 * MBy);
    ushort* W1l   = (ushort*)(Wb + 24 * MBy);
    ushort* Hih   = (ushort*)(Wb + 80 * MBy);   // 32MB: 80-112
    ushort* Hil   = (ushort*)(Wb + 48 * MBy);   // 32MB: 48-80
    ushort* W2h   = (ushort*)(Wb + 16 * MBy);
    ushort* W2l   = (ushort*)(Wb + 24 * MBy);
    float*  Y0    = (float*)(Wb + 32 * MBy);
    float*  Y1    = (float*)d_out;              // scratch until final LN

    const int M = B_ * NQ_;
    const int n4act = M * D_ / 4;
    dim3 blk(256);
    dim3 gQKV(D_ / 128, M / 128, 3);
    dim3 gSK(D_ / 128, M / 128, 2);
    dim3 gF(DFF_ / 128, M / 128);

    split_rows<<<n4act / 256, blk, 0, stream>>>(Q, Qh, Ql, n4act);
    split_rows<<<n4act / 256, blk, 0, stream>>>(K, Kh, Kl, n4act);
    split_tr<<<dim3(D_/32, D_/32), blk, 0, stream>>>(Wq, Wqh, Wql, D_, D_);
    split_tr<<<dim3(D_/32, D_/32), blk, 0, stream>>>(Wk, Wkh, Wkl, D_, D_);
    split_tr<<<dim3(D_/32, D_/32), blk, 0, stream>>>(Wv, Wvh, Wvl, D_, D_);
    split_tr<<<dim3(D_/32, D_/32), blk, 0, stream>>>(Wo, Woh, Wol, D_, D_);

    QkvArgs qa;
    qa.Ah[0] = Qh;  qa.Al[0] = Ql;  qa.Bh[0] = Wqh; qa.Bl[0] = Wql; qa.bias[0] = bq; qa.Co[0] = qhp;
    qa.Ah[1] = Kh;  qa.Al[1] = Kl;  qa.Bh[1] = Wkh; qa.Bl[1] = Wkl; qa.bias[1] = bk; qa.Co[1] = khp;
    qa.Ah[2] = Kh;  qa.Al[2] = Kl;  qa.Bh[2] = Wvh; qa.Bl[2] = Wvl; qa.bias[2] = bv; qa.Co[2] = vhp;
    gemm_qkv<<<gQKV, blk, 0, stream>>>(qa, M, D_, D_);

    flash_attn_mfma<<<dim3(1024), blk, 0, stream>>>(qhp, khp, vhp, aOh, aOl);

    // output projection, split-K=2 (2 blocks/CU) + fused 3-input LN
    gemm_splitk2<<<gSK, blk, 0, stream>>>(aOh, aOl, Woh, Wol, bo, oprj0, oprj1, M, D_, D_);
    add_ln3<true><<<M, blk, 0, stream>>>(oprj0, oprj1, Q, g0, be0, Xf, Xh, Xl);

    split_tr<<<dim3(DFF_/32, D_/32), blk, 0, stream>>>(W1, W1h, W1l, D_, DFF_);
    gemm_mfma<true,1><<<gF, blk, 0, stream>>>(Xh, Xl, W1h, W1l, b1, nullptr, Hih, Hil, M, DFF_, D_);
    split_tr<<<dim3(D_/32, DFF_/32), blk, 0, stream>>>(W2, W2h, W2l, DFF_, D_);

    // FFN2, split-K=2; Y1 uses d_out as scratch (dead until final LN)
    gemm_splitk2<<<gSK, blk, 0, stream>>>(Hih, Hil, W2h, W2l, b2, Y0, Y1, M, D_, DFF_);
    add_ln3<false><<<M, blk, 0, stream>>>(Y0, Y1, Xf, g1, be1, (float*)d_out, nullptr, nullptr);
}

// Round 13
// 396.852 us; speedup vs baseline: 1.3948x; 1.0414x over previous
//
#include <hip/hip_runtime.h>
#include <math.h>

#define B_   4
#define NQ_  1024
#define NK_  1024
#define D_   1024
#define H_   16
#define DH_  64
#define DFF_ 4096
#define SCALE_ (1.0f/32.0f)   // 1/sqrt(D)
#define LN_EPS_ 1e-5f

typedef __attribute__((ext_vector_type(8))) short bf16x8_t;  // 8 bf16 = 4 VGPR
typedef __attribute__((ext_vector_type(4))) float f32x4_t;

__device__ __forceinline__ ushort f2bf_rne(float x) {
    unsigned u = __float_as_uint(x);
    unsigned r = (u + 0x7FFFu + ((u >> 16) & 1u)) >> 16;
    return (ushort)r;
}
__device__ __forceinline__ float bf2f(ushort h) {
    return __uint_as_float(((unsigned)h) << 16);
}

// async global->LDS, 16B per lane. LDS dest = wave-uniform base + lane*16.
__device__ __forceinline__ void gl_lds16(const ushort* g, ushort* l) {
    __builtin_amdgcn_global_load_lds(
        (const __attribute__((address_space(1))) unsigned int*)g,
        (__attribute__((address_space(3))) unsigned int*)l, 16, 0, 0);
}

// ---------------------------------------------------------------------------
// fp32 -> (hi,lo) bf16 planes.
// ---------------------------------------------------------------------------
__global__ __launch_bounds__(256) void split_rows(const float* __restrict__ src,
        ushort* __restrict__ hi, ushort* __restrict__ lo, int n4)
{
    int i = blockIdx.x * 256 + threadIdx.x;
    if (i >= n4) return;
    float4 v = ((const float4*)src)[i];
    ushort4 h, l;
    h.x = f2bf_rne(v.x); l.x = f2bf_rne(v.x - bf2f(h.x));
    h.y = f2bf_rne(v.y); l.y = f2bf_rne(v.y - bf2f(h.y));
    h.z = f2bf_rne(v.z); l.z = f2bf_rne(v.z - bf2f(h.z));
    h.w = f2bf_rne(v.w); l.w = f2bf_rne(v.w - bf2f(h.w));
    ((ushort4*)hi)[i] = h;
    ((ushort4*)lo)[i] = l;
}

// ---------------------------------------------------------------------------
// Weight split + transpose: W[K][N] fp32 -> planes Wt[N][K] bf16.
// ---------------------------------------------------------------------------
__global__ __launch_bounds__(256) void split_tr(const float* __restrict__ Wsrc,
        ushort* __restrict__ th, ushort* __restrict__ tl, int K, int N)
{
    __shared__ float tile[32][33];
    const int nb = blockIdx.x * 32, kb = blockIdx.y * 32;
    const int t = threadIdx.x;
    {
        int r = t >> 3, c4 = (t & 7) * 4;
        float4 v = *(const float4*)&Wsrc[(size_t)(kb + r) * N + nb + c4];
        tile[r][c4 + 0] = v.x; tile[r][c4 + 1] = v.y;
        tile[r][c4 + 2] = v.z; tile[r][c4 + 3] = v.w;
    }
    __syncthreads();
    {
        int n = t >> 3, k4 = (t & 7) * 4;
        float a0 = tile[k4 + 0][n], a1 = tile[k4 + 1][n];
        float a2 = tile[k4 + 2][n], a3 = tile[k4 + 3][n];
        ushort4 h, l;
        h.x = f2bf_rne(a0); l.x = f2bf_rne(a0 - bf2f(h.x));
        h.y = f2bf_rne(a1); l.y = f2bf_rne(a1 - bf2f(h.y));
        h.z = f2bf_rne(a2); l.z = f2bf_rne(a2 - bf2f(h.z));
        h.w = f2bf_rne(a3); l.w = f2bf_rne(a3 - bf2f(h.w));
        size_t o = (size_t)(nb + n) * K + kb + k4;
        *(ushort4*)&th[o] = h;
        *(ushort4*)&tl[o] = l;
    }
}

// bijective XCD-chunked swizzle (nwg % 8 == 0 for all our grids)
__device__ __forceinline__ void swz_block(int& brow, int& bcol, int tile) {
    const int nx  = gridDim.x;
    const int lin = blockIdx.y * nx + blockIdx.x;
    const int cpx = (nx * gridDim.y) >> 3;
    const int swz = (lin & 7) * cpx + (lin >> 3);
    brow = (swz / nx) * tile;
    bcol = (swz % nx) * tile;
}

// ---------------------------------------------------------------------------
// MFMA GEMM body (r10-validated counted-vmcnt fine-phase pipeline). 128^2.
// Kd = row stride; Klen = K extent of this block's work (split-K window).
// bias == nullptr -> no bias. OMODE: 0 fp32, 1 split planes, 2 hi-only.
// ---------------------------------------------------------------------------
template<bool RELU, int OMODE>
__device__ __forceinline__ void gemm_body(
        const ushort* __restrict__ Ah, const ushort* __restrict__ Al,
        const ushort* __restrict__ Bh, const ushort* __restrict__ Bl,
        const float* __restrict__ bias,
        float* __restrict__ C, ushort* __restrict__ Ch, ushort* __restrict__ Cl,
        int M, int N, int Kd, int Klen, int brow, int bcol)
{
    __shared__ __align__(16) ushort S[2][4][128 * 32];   // 64KB dbuf

    const int t    = threadIdx.x;
    const int lane = t & 63;
    const int w    = t >> 6;
    const int wr   = (w >> 1) * 64;
    const int wc   = (w & 1) * 64;
    const int fr   = lane & 15;
    const int g    = lane >> 4;
    const int sS   = ((g ^ ((fr >> 1) & 3)) << 3);
    const int cl   = lane & 15;
    const int rq   = (lane >> 4) * 4;

    float bpre[4];
    #pragma unroll
    for (int j = 0; j < 4; ++j)
        bpre[j] = bias ? bias[bcol + wc + j * 16 + cl] : 0.f;

    f32x4_t acc[4][4];
    #pragma unroll
    for (int i = 0; i < 4; ++i)
        #pragma unroll
        for (int j = 0; j < 4; ++j)
            acc[i][j] = (f32x4_t){0.f, 0.f, 0.f, 0.f};

    const int lrow  = lane >> 2;
    const int lslot = ((lane & 3) ^ ((lane >> 3) & 3)) << 3;
    const int c0    = w * 2;

    auto issue2 = [&](const ushort* gpp, int rb, int pl, int buf, int k0) {
        #pragma unroll
        for (int ii = 0; ii < 2; ++ii) {
            int c = c0 + ii;
            gl_lds16(gpp + (size_t)(rb + c * 16 + lrow) * Kd + k0 + lslot,
                     &S[buf][pl][c * 512]);
        }
    };

    bf16x8_t ahf[4], bhf[4], blf[4], alf[4];

    issue2(Ah, brow, 0, 0, 0);
    issue2(Bh, bcol, 2, 0, 0);
    issue2(Bl, bcol, 3, 0, 0);
    issue2(Al, brow, 1, 0, 0);
    asm volatile("s_waitcnt vmcnt(4)" ::: "memory");
    __builtin_amdgcn_s_barrier();

    const int NT = Klen >> 5;
    for (int tt = 0; tt < NT; ++tt) {
        const int cur = tt & 1, nxt = cur ^ 1;
        const int kn  = (tt + 1) << 5;
        const bool more = (tt + 1 < NT);

        // phase 0: hh
        #pragma unroll
        for (int i = 0; i < 4; ++i)
            ahf[i] = *(const bf16x8_t*)&S[cur][0][(wr + i * 16 + fr) * 32 + sS];
        #pragma unroll
        for (int j = 0; j < 4; ++j)
            bhf[j] = *(const bf16x8_t*)&S[cur][2][(wc + j * 16 + fr) * 32 + sS];
        if (more) {
            issue2(Ah, brow, 0, nxt, kn);
            issue2(Bh, bcol, 2, nxt, kn);
            asm volatile("s_waitcnt vmcnt(6)" ::: "memory");
        } else {
            asm volatile("s_waitcnt vmcnt(2)" ::: "memory");
        }
        __builtin_amdgcn_s_barrier();
        asm volatile("s_waitcnt lgkmcnt(0)" ::: "memory");
        __builtin_amdgcn_sched_barrier(0);
        __builtin_amdgcn_s_setprio(1);
        #pragma unroll
        for (int i = 0; i < 4; ++i)
            #pragma unroll
            for (int j = 0; j < 4; ++j)
                acc[i][j] = __builtin_amdgcn_mfma_f32_16x16x32_bf16(ahf[i], bhf[j], acc[i][j], 0, 0, 0);
        __builtin_amdgcn_s_setprio(0);
        __builtin_amdgcn_s_barrier();

        // phase 1: hl
        #pragma unroll
        for (int j = 0; j < 4; ++j)
            blf[j] = *(const bf16x8_t*)&S[cur][3][(wc + j * 16 + fr) * 32 + sS];
        if (more) {
            issue2(Bl, bcol, 3, nxt, kn);
            asm volatile("s_waitcnt vmcnt(6)" ::: "memory");
        } else {
            asm volatile("s_waitcnt vmcnt(0)" ::: "memory");
        }
        __builtin_amdgcn_s_barrier();
        asm volatile("s_waitcnt lgkmcnt(0)" ::: "memory");
        __builtin_amdgcn_sched_barrier(0);
        __builtin_amdgcn_s_setprio(1);
        #pragma unroll
        for (int i = 0; i < 4; ++i)
            #pragma unroll
            for (int j = 0; j < 4; ++j)
                acc[i][j] = __builtin_amdgcn_mfma_f32_16x16x32_bf16(ahf[i], blf[j], acc[i][j], 0, 0, 0);
        __builtin_amdgcn_s_setprio(0);
        __builtin_amdgcn_s_barrier();

        // phase 2: lh
        #pragma unroll
        for (int i = 0; i < 4; ++i)
            alf[i] = *(const bf16x8_t*)&S[cur][1][(wr + i * 16 + fr) * 32 + sS];
        if (more) {
            issue2(Al, brow, 1, nxt, kn);
            asm volatile("s_waitcnt vmcnt(4)" ::: "memory");
        }
        __builtin_amdgcn_s_barrier();
        asm volatile("s_waitcnt lgkmcnt(0)" ::: "memory");
        __builtin_amdgcn_sched_barrier(0);
        __builtin_amdgcn_s_setprio(1);
        #pragma unroll
        for (int i = 0; i < 4; ++i)
            #pragma unroll
            for (int j = 0; j < 4; ++j)
                acc[i][j] = __builtin_amdgcn_mfma_f32_16x16x32_bf16(alf[i], bhf[j], acc[i][j], 0, 0, 0);
        __builtin_amdgcn_s_setprio(0);
        __builtin_amdgcn_s_barrier();
    }

    if (OMODE == 0) {
        #pragma unroll
        for (int j = 0; j < 4; ++j) {
            int col = bcol + wc + j * 16 + cl;
            #pragma unroll
            for (int i = 0; i < 4; ++i)
                #pragma unroll
                for (int r = 0; r < 4; ++r) {
                    int row = brow + wr + i * 16 + rq + r;
                    float v = acc[i][j][r] + bpre[j];
                    if (RELU) v = fmaxf(v, 0.f);
                    C[(size_t)row * N + col] = v;
                }
        }
    } else {
        float* E = (float*)&S[0][0][0] + w * 4096;   // 16KB per wave
        #pragma unroll
        for (int j = 0; j < 4; ++j) {
            #pragma unroll
            for (int i = 0; i < 4; ++i)
                #pragma unroll
                for (int r = 0; r < 4; ++r) {
                    float v = acc[i][j][r] + bpre[j];
                    if (RELU) v = fmaxf(v, 0.f);
                    E[(i * 16 + rq + r) * 64 + j * 16 + cl] = v;
                }
        }
        __syncthreads();
        const int rr8 = lane >> 3;
        const int c8  = (lane & 7) * 8;
        #pragma unroll
        for (int p = 0; p < 8; ++p) {
            int rl = p * 8 + rr8;
            float4 va = *(float4*)&E[rl * 64 + c8];
            float4 vb = *(float4*)&E[rl * 64 + c8 + 4];
            float v[8] = {va.x, va.y, va.z, va.w, vb.x, vb.y, vb.z, vb.w};
            bf16x8_t hv, lv;
            #pragma unroll
            for (int q = 0; q < 8; ++q) {
                ushort hh = f2bf_rne(v[q]);
                hv[q] = (short)hh;
                lv[q] = (short)f2bf_rne(v[q] - bf2f(hh));
            }
            size_t o = (size_t)(brow + wr + rl) * N + (bcol + wc + c8);
            *(bf16x8_t*)&Ch[o] = hv;
            if (OMODE == 1) *(bf16x8_t*)&Cl[o] = lv;
        }
    }
}

template<bool RELU, int OMODE>
__global__ __launch_bounds__(256) void gemm_mfma(
        const ushort* __restrict__ Ah, const ushort* __restrict__ Al,
        const ushort* __restrict__ Bh, const ushort* __restrict__ Bl,
        const float* __restrict__ bias,
        float* __restrict__ C, ushort* __restrict__ Ch, ushort* __restrict__ Cl,
        int M, int N, int Kd)
{
    int brow, bcol;
    swz_block(brow, bcol, 128);
    gemm_body<RELU, OMODE>(Ah, Al, Bh, Bl, bias, C, Ch, Cl, M, N, Kd, Kd, brow, bcol);
}

// split-K=2: grid.z picks K-window; z=0 carries bias -> C0, z=1 -> C1.
__global__ __launch_bounds__(256) void gemm_splitk2(
        const ushort* __restrict__ Ah, const ushort* __restrict__ Al,
        const ushort* __restrict__ Bh, const ushort* __restrict__ Bl,
        const float* __restrict__ bias,
        float* __restrict__ C0, float* __restrict__ C1,
        int M, int N, int Kd)
{
    int brow, bcol;
    swz_block(brow, bcol, 128);
    const int z = blockIdx.z;
    const int Kh2 = Kd >> 1;
    const int ko  = z * Kh2;
    gemm_body<false, 0>(Ah + ko, Al + ko, Bh + ko, Bl + ko,
                        z == 0 ? bias : nullptr,
                        z == 0 ? C0 : C1, nullptr, nullptr,
                        M, N, Kd, Kh2, brow, bcol);
}

// q/k/v projections fused into one dispatch (grid.z = 3 -> 768 blocks)
struct QkvArgs {
    const ushort* Ah[3]; const ushort* Al[3];
    const ushort* Bh[3]; const ushort* Bl[3];
    const float*  bias[3];
    ushort*       Co[3];
};

__global__ __launch_bounds__(256) void gemm_qkv(QkvArgs qa, int M, int N, int Kd)
{
    int brow, bcol;
    swz_block(brow, bcol, 128);
    const int z = blockIdx.z;
    gemm_body<false, 2>(qa.Ah[z], qa.Al[z], qa.Bh[z], qa.Bl[z], qa.bias[z],
                        nullptr, qa.Co[z], nullptr, M, N, Kd, Kd, brow, bcol);
}

// ---------------------------------------------------------------------------
// FFN1 r13: 256^2 tile, 8 waves (512 thr), SAME counted-vmcnt ring as r10
// (G0=[Ah,Bh]=4 issues/wave, G1=[Bl]=2, G2=[Al]=2; waits 6/6/4 steady,
// 2/0/- last tile; 1-tile skew). Wave grid 2Mx4N -> per-wave 128x64,
// acc[8][4]. LDS 128KB dbuf -> 1 block/CU, 8 self-covering waves.
// Epilogue: 2-pass per-wave 16KB bounce, coalesced split-plane stores.
// Per-element arithmetic identical to gemm_body (hh,hl,lh order).
// ---------------------------------------------------------------------------
__global__ __launch_bounds__(512) void gemm_ffn1_256(
        const ushort* __restrict__ Ah, const ushort* __restrict__ Al,
        const ushort* __restrict__ Bh, const ushort* __restrict__ Bl,
        const float* __restrict__ bias,
        ushort* __restrict__ Ch, ushort* __restrict__ Cl,
        int M, int N, int Kd)
{
    __shared__ __align__(16) ushort S[2][4][256 * 32];   // 128KB

    const int t    = threadIdx.x;
    const int lane = t & 63;
    const int w    = t >> 6;
    const int wr   = (w >> 2) * 128;   // 2 M-halves
    const int wc   = (w & 3) * 64;     // 4 N-quarters
    const int fr   = lane & 15;
    const int g    = lane >> 4;
    const int sS   = ((g ^ ((fr >> 1) & 3)) << 3);
    const int cl   = lane & 15;
    const int rq   = (lane >> 4) * 4;

    int brow, bcol;
    swz_block(brow, bcol, 256);

    float bpre[4];
    #pragma unroll
    for (int j = 0; j < 4; ++j) bpre[j] = bias[bcol + wc + j * 16 + cl];

    f32x4_t acc[8][4];
    #pragma unroll
    for (int i = 0; i < 8; ++i)
        #pragma unroll
        for (int j = 0; j < 4; ++j)
            acc[i][j] = (f32x4_t){0.f, 0.f, 0.f, 0.f};

    const int lrow  = lane >> 2;
    const int lslot = ((lane & 3) ^ ((lane >> 3) & 3)) << 3;
    const int c0    = w * 2;   // 8 waves x 2 chunks = 16 chunks (256 rows)

    auto issue2 = [&](const ushort* gpp, int rb, int pl, int buf, int k0) {
        #pragma unroll
        for (int ii = 0; ii < 2; ++ii) {
            int c = c0 + ii;
            gl_lds16(gpp + (size_t)(rb + c * 16 + lrow) * Kd + k0 + lslot,
                     &S[buf][pl][c * 512]);
        }
    };

    bf16x8_t ahf[8], bhf[4], blf[4], alf[8];

    issue2(Ah, brow, 0, 0, 0);
    issue2(Bh, bcol, 2, 0, 0);
    issue2(Bl, bcol, 3, 0, 0);
    issue2(Al, brow, 1, 0, 0);
    asm volatile("s_waitcnt vmcnt(4)" ::: "memory");
    __builtin_amdgcn_s_barrier();

    const int NT = Kd >> 5;
    for (int tt = 0; tt < NT; ++tt) {
        const int cur = tt & 1, nxt = cur ^ 1;
        const int kn  = (tt + 1) << 5;
        const bool more = (tt + 1 < NT);

        // phase 0: hh
        #pragma unroll
        for (int i = 0; i < 8; ++i)
            ahf[i] = *(const bf16x8_t*)&S[cur][0][(wr + i * 16 + fr) * 32 + sS];
        #pragma unroll
        for (int j = 0; j < 4; ++j)
            bhf[j] = *(const bf16x8_t*)&S[cur][2][(wc + j * 16 + fr) * 32 + sS];
        if (more) {
            issue2(Ah, brow, 0, nxt, kn);
            issue2(Bh, bcol, 2, nxt, kn);
            asm volatile("s_waitcnt vmcnt(6)" ::: "memory");
        } else {
            asm volatile("s_waitcnt vmcnt(2)" ::: "memory");
        }
        __builtin_amdgcn_s_barrier();
        asm volatile("s_waitcnt lgkmcnt(0)" ::: "memory");
        __builtin_amdgcn_sched_barrier(0);
        __builtin_amdgcn_s_setprio(1);
        #pragma unroll
        for (int i = 0; i < 8; ++i)
            #pragma unroll
            for (int j = 0; j < 4; ++j)
                acc[i][j] = __builtin_amdgcn_mfma_f32_16x16x32_bf16(ahf[i], bhf[j], acc[i][j], 0, 0, 0);
        __builtin_amdgcn_s_setprio(0);
        __builtin_amdgcn_s_barrier();

        // phase 1: hl
        #pragma unroll
        for (int j = 0; j < 4; ++j)
            blf[j] = *(const bf16x8_t*)&S[cur][3][(wc + j * 16 + fr) * 32 + sS];
        if (more) {
            issue2(Bl, bcol, 3, nxt, kn);
            asm volatile("s_waitcnt vmcnt(6)" ::: "memory");
        } else {
            asm volatile("s_waitcnt vmcnt(0)" ::: "memory");
        }
        __builtin_amdgcn_s_barrier();
        asm volatile("s_waitcnt lgkmcnt(0)" ::: "memory");
        __builtin_amdgcn_sched_barrier(0);
        __builtin_amdgcn_s_setprio(1);
        #pragma unroll
        for (int i = 0; i < 8; ++i)
            #pragma unroll
            for (int j = 0; j < 4; ++j)
                acc[i][j] = __builtin_amdgcn_mfma_f32_16x16x32_bf16(ahf[i], blf[j], acc[i][j], 0, 0, 0);
        __builtin_amdgcn_s_setprio(0);
        __builtin_amdgcn_s_barrier();

        // phase 2: lh
        #pragma unroll
        for (int i = 0; i < 8; ++i)
            alf[i] = *(const bf16x8_t*)&S[cur][1][(wr + i * 16 + fr) * 32 + sS];
        if (more) {
            issue2(Al, brow, 1, nxt, kn);
            asm volatile("s_waitcnt vmcnt(4)" ::: "memory");
        }
        __builtin_amdgcn_s_barrier();
        asm volatile("s_waitcnt lgkmcnt(0)" ::: "memory");
        __builtin_amdgcn_sched_barrier(0);
        __builtin_amdgcn_s_setprio(1);
        #pragma unroll
        for (int i = 0; i < 8; ++i)
            #pragma unroll
            for (int j = 0; j < 4; ++j)
                acc[i][j] = __builtin_amdgcn_mfma_f32_16x16x32_bf16(alf[i], bhf[j], acc[i][j], 0, 0, 0);
        __builtin_amdgcn_s_setprio(0);
        __builtin_amdgcn_s_barrier();
    }

    // epilogue: 2-pass per-wave bounce (16KB slice), bias+ReLU+split stores
    __syncthreads();
    float* E = (float*)&S[0][0][0] + w * 4096;   // 4096 f32 = 64x64
    const int rr8 = lane >> 3;
    const int c8  = (lane & 7) * 8;
    #pragma unroll
    for (int pass = 0; pass < 2; ++pass) {
        #pragma unroll
        for (int i = 0; i < 4; ++i) {
            #pragma unroll
            for (int j = 0; j < 4; ++j)
                #pragma unroll
                for (int r = 0; r < 4; ++r) {
                    float v = fmaxf(acc[pass * 4 + i][j][r] + bpre[j], 0.f);
                    E[(i * 16 + rq + r) * 64 + j * 16 + cl] = v;
                }
        }
        // same-wave DS ordering guarantees write->read visibility
        #pragma unroll
        for (int p = 0; p < 8; ++p) {
            int rl = p * 8 + rr8;
            float4 va = *(float4*)&E[rl * 64 + c8];
            float4 vb = *(float4*)&E[rl * 64 + c8 + 4];
            float v[8] = {va.x, va.y, va.z, va.w, vb.x, vb.y, vb.z, vb.w};
            bf16x8_t hv, lv;
            #pragma unroll
            for (int q = 0; q < 8; ++q) {
                ushort hh = f2bf_rne(v[q]);
                hv[q] = (short)hh;
                lv[q] = (short)f2bf_rne(v[q] - bf2f(hh));
            }
            size_t o = (size_t)(brow + wr + pass * 64 + rl) * N + (bcol + wc + c8);
            *(bf16x8_t*)&Ch[o] = hv;
            *(bf16x8_t*)&Cl[o] = lv;
        }
    }
}

// ---------------------------------------------------------------------------
// MFMA flash attention v2 (r12-validated): swapped operands, per-lane
// softmax state, T14 reg prefetch, coalesced transposed epilogue.
// ---------------------------------------------------------------------------
__global__ __launch_bounds__(256) void flash_attn_mfma(
        const ushort* __restrict__ qh, const ushort* __restrict__ kh,
        const ushort* __restrict__ vh,
        ushort* __restrict__ Oh, ushort* __restrict__ Ol)
{
    __shared__ __align__(16) ushort SMEM[8192];   // 16KB, carved below
    ushort* sk  = SMEM;           // [32][72]  K tile (2304 ushorts)
    ushort* svt = SMEM + 2304;    // [64][40]  V^T tile (2560)
    ushort* pw0 = SMEM + 4864;    // [4][16][40] per-wave P (2560)

    const int bid  = blockIdx.x;
    const int slot = bid >> 3;
    const int bh   = (bid & 7) * 8 + (slot >> 4);
    const int qt   = slot & 15;
    const int b    = bh >> 4;
    const int h    = bh & 15;
    const int qb   = qt * 64;

    const int t = threadIdx.x, lane = t & 63, w = t >> 6;
    const int l15 = lane & 15, g = lane >> 4;

    bf16x8_t qf[2];
    {
        size_t qrow = ((size_t)(b * NQ_) + qb + w * 16 + l15) * D_ + h * DH_;
        qf[0] = *(const bf16x8_t*)&qh[qrow + 0  + 8 * g];
        qf[1] = *(const bf16x8_t*)&qh[qrow + 32 + 8 * g];
    }

    f32x4_t acc[4];   // O^T[d = 16*dt + 4g + r][q = l15]
    #pragma unroll
    for (int dt = 0; dt < 4; ++dt) acc[dt] = (f32x4_t){0.f, 0.f, 0.f, 0.f};
    float m = -INFINITY, l = 0.0f;

    const int kkv = t >> 3,  kds = (t & 7) * 8;
    const int vkv = t & 31,  vds = (t >> 5) * 8;
    const size_t kvbase = (size_t)(b * NK_) * D_ + h * DH_;

    bf16x8_t kreg = *(const bf16x8_t*)&kh[kvbase + (size_t)kkv * D_ + kds];
    bf16x8_t vreg = *(const bf16x8_t*)&vh[kvbase + (size_t)vkv * D_ + vds];

    ushort* pw = pw0 + w * 640;

    for (int kt = 0; kt < NK_; kt += 32) {
        __syncthreads();
        *(bf16x8_t*)&sk[kkv * 72 + kds] = kreg;
        #pragma unroll
        for (int j = 0; j < 8; ++j)
            svt[(vds + j) * 40 + vkv] = (ushort)vreg[j];
        __syncthreads();
        if (kt + 32 < NK_) {
            kreg = *(const bf16x8_t*)&kh[kvbase + (size_t)(kt + 32 + kkv) * D_ + kds];
            vreg = *(const bf16x8_t*)&vh[kvbase + (size_t)(kt + 32 + vkv) * D_ + vds];
        }

        f32x4_t s0 = (f32x4_t){0.f,0.f,0.f,0.f};
        f32x4_t s1 = (f32x4_t){0.f,0.f,0.f,0.f};
        #pragma unroll
        for (int c = 0; c < 2; ++c) {
            bf16x8_t k0 = *(const bf16x8_t*)&sk[(l15     ) * 72 + 32 * c + 8 * g];
            bf16x8_t k1 = *(const bf16x8_t*)&sk[(l15 + 16) * 72 + 32 * c + 8 * g];
            s0 = __builtin_amdgcn_mfma_f32_16x16x32_bf16(k0, qf[c], s0, 0, 0, 0);
            s1 = __builtin_amdgcn_mfma_f32_16x16x32_bf16(k1, qf[c], s1, 0, 0, 0);
        }

        float e0[4], e1[4];
        #pragma unroll
        for (int r = 0; r < 4; ++r) { e0[r] = s0[r] * SCALE_; e1[r] = s1[r] * SCALE_; }
        float tmax = fmaxf(fmaxf(fmaxf(e0[0], e0[1]), fmaxf(e0[2], e0[3])),
                           fmaxf(fmaxf(e1[0], e1[1]), fmaxf(e1[2], e1[3])));
        tmax = fmaxf(tmax, __shfl_xor(tmax, 16, 64));
        tmax = fmaxf(tmax, __shfl_xor(tmax, 32, 64));
        float mn   = fmaxf(m, tmax);
        float corr = __expf(m - mn);
        float p0[4], p1[4];
        float ps = 0.f;
        #pragma unroll
        for (int r = 0; r < 4; ++r) {
            p0[r] = __expf(e0[r] - mn);
            p1[r] = __expf(e1[r] - mn);
            ps += p0[r] + p1[r];
        }
        ps += __shfl_xor(ps, 16, 64);
        ps += __shfl_xor(ps, 32, 64);
        l = l * corr + ps;
        m = mn;
        #pragma unroll
        for (int dt = 0; dt < 4; ++dt)
            #pragma unroll
            for (int r = 0; r < 4; ++r)
                acc[dt][r] *= corr;

        ushort4 pk0, pk1;
        pk0.x = f2bf_rne(p0[0]); pk0.y = f2bf_rne(p0[1]);
        pk0.z = f2bf_rne(p0[2]); pk0.w = f2bf_rne(p0[3]);
        pk1.x = f2bf_rne(p1[0]); pk1.y = f2bf_rne(p1[1]);
        pk1.z = f2bf_rne(p1[2]); pk1.w = f2bf_rne(p1[3]);
        *(ushort4*)&pw[l15 * 40 + 4 * g]      = pk0;
        *(ushort4*)&pw[l15 * 40 + 16 + 4 * g] = pk1;
        bf16x8_t pa = *(const bf16x8_t*)&pw[l15 * 40 + 8 * g];

        #pragma unroll
        for (int dt = 0; dt < 4; ++dt) {
            bf16x8_t vf = *(const bf16x8_t*)&svt[(16 * dt + l15) * 40 + 8 * g];
            acc[dt] = __builtin_amdgcn_mfma_f32_16x16x32_bf16(vf, pa, acc[dt], 0, 0, 0);
        }
    }

    __syncthreads();
    float invl = 1.0f / l;
    float* Ew = (float*)SMEM + w * 1024;
    #pragma unroll
    for (int dt = 0; dt < 4; ++dt)
        #pragma unroll
        for (int r = 0; r < 4; ++r)
            Ew[(16 * dt + 4 * g + r) * 16 + l15] = acc[dt][r] * invl;
    const int ql = lane >> 2;
    const int dc = (lane & 3) * 16;
    float ov[16];
    #pragma unroll
    for (int j = 0; j < 16; ++j) ov[j] = Ew[(dc + j) * 16 + ql];
    bf16x8_t hv0, hv1, lv0, lv1;
    #pragma unroll
    for (int j = 0; j < 8; ++j) {
        ushort ha = f2bf_rne(ov[j]);
        ushort hb = f2bf_rne(ov[8 + j]);
        hv0[j] = (short)ha; lv0[j] = (short)f2bf_rne(ov[j] - bf2f(ha));
        hv1[j] = (short)hb; lv1[j] = (short)f2bf_rne(ov[8 + j] - bf2f(hb));
    }
    size_t orow = ((size_t)(b * NQ_) + qb + w * 16 + ql) * D_ + h * DH_ + dc;
    *(bf16x8_t*)&Oh[orow]     = hv0;
    *(bf16x8_t*)&Oh[orow + 8] = hv1;
    *(bf16x8_t*)&Ol[orow]     = lv0;
    *(bf16x8_t*)&Ol[orow + 8] = lv1;
}

// ---------------------------------------------------------------------------
// out = LayerNorm(a0 + a1 + r) * g + be. SPLIT: also emit bf16 hi/lo planes.
// ---------------------------------------------------------------------------
template<bool SPLIT>
__global__ __launch_bounds__(256) void add_ln3(const float* __restrict__ a0,
        const float* __restrict__ a1, const float* __restrict__ r,
        const float* __restrict__ g, const float* __restrict__ be,
        float* __restrict__ out, ushort* __restrict__ oh, ushort* __restrict__ ol)
{
    const int row = blockIdx.x;
    const int t = threadIdx.x;
    float vals[4];
    float s1 = 0.0f, s2 = 0.0f;
    #pragma unroll
    for (int i = 0; i < 4; ++i) {
        int col = t + i * 256;
        size_t o = (size_t)row * D_ + col;
        float vv = a0[o] + a1[o] + r[o];
        vals[i] = vv;
        s1 += vv;
        s2 += vv * vv;
    }
    #pragma unroll
    for (int off = 32; off > 0; off >>= 1) {
        s1 += __shfl_down(s1, off, 64);
        s2 += __shfl_down(s2, off, 64);
    }
    __shared__ float p1[4], p2[4];
    const int wave = t >> 6;
    if ((t & 63) == 0) { p1[wave] = s1; p2[wave] = s2; }
    __syncthreads();
    s1 = p1[0] + p1[1] + p1[2] + p1[3];
    s2 = p2[0] + p2[1] + p2[2] + p2[3];
    const float mean = s1 * (1.0f / D_);
    const float var  = s2 * (1.0f / D_) - mean * mean;
    const float rstd = rsqrtf(var + LN_EPS_);
    #pragma unroll
    for (int i = 0; i < 4; ++i) {
        int col = t + i * 256;
        float v = (vals[i] - mean) * rstd * g[col] + be[col];
        out[(size_t)row * D_ + col] = v;
        if (SPLIT) {
            ushort h = f2bf_rne(v);
            oh[(size_t)row * D_ + col] = h;
            ol[(size_t)row * D_ + col] = f2bf_rne(v - bf2f(h));
        }
    }
}

// ---------------------------------------------------------------------------
extern "C" void kernel_launch(void* const* d_in, const int* in_sizes, int n_in,
                              void* d_out, int out_size, void* d_ws, size_t ws_size,
                              hipStream_t stream)
{
    const float* Q   = (const float*)d_in[0];
    const float* K   = (const float*)d_in[1];
    const float* Wq  = (const float*)d_in[2];
    const float* bq  = (const float*)d_in[3];
    const float* Wk  = (const float*)d_in[4];
    const float* bk  = (const float*)d_in[5];
    const float* Wv  = (const float*)d_in[6];
    const float* bv  = (const float*)d_in[7];
    const float* Wo  = (const float*)d_in[8];
    const float* bo  = (const float*)d_in[9];
    const float* W1  = (const float*)d_in[10];
    const float* b1  = (const float*)d_in[11];
    const float* W2  = (const float*)d_in[12];
    const float* b2  = (const float*)d_in[13];
    const float* g0  = (const float*)d_in[14];
    const float* be0 = (const float*)d_in[15];
    const float* g1  = (const float*)d_in[16];
    const float* be1 = (const float*)d_in[17];

    unsigned char* Wb = (unsigned char*)d_ws;
    const size_t MBy = 1ull << 20;

    ushort* Qh   = (ushort*)(Wb +  0 * MBy);
    ushort* Ql   = (ushort*)(Wb +  8 * MBy);
    ushort* Kh   = (ushort*)(Wb + 16 * MBy);
    ushort* Kl   = (ushort*)(Wb + 24 * MBy);
    ushort* Wqh  = (ushort*)(Wb + 32 * MBy);
    ushort* Wql  = (ushort*)(Wb + 34 * MBy);
    ushort* Wkh  = (ushort*)(Wb + 36 * MBy);
    ushort* Wkl  = (ushort*)(Wb + 38 * MBy);
    ushort* Wvh  = (ushort*)(Wb + 40 * MBy);
    ushort* Wvl  = (ushort*)(Wb + 42 * MBy);
    ushort* Woh  = (ushort*)(Wb + 44 * MBy);
    ushort* Wol  = (ushort*)(Wb + 46 * MBy);
    ushort* qhp  = (ushort*)(Wb + 48 * MBy);
    ushort* khp  = (ushort*)(Wb + 56 * MBy);
    ushort* vhp  = (ushort*)(Wb + 64 * MBy);
    ushort* aOh  = (ushort*)(Wb + 72 * MBy);
    ushort* aOl  = (ushort*)(Wb + 80 * MBy);

    float*  oprj0 = (float*)(Wb + 16 * MBy);
    float*  oprj1 = (float*)(Wb + 56 * MBy);
    float*  Xf    = (float*)(Wb +  0 * MBy);
    ushort* Xh    = (ushort*)(Wb + 32 * MBy);
    ushort* Xl    = (ushort*)(Wb + 40 * MBy);
    ushort* W1h   = (ushort*)(Wb + 16 * MBy);
    ushort* W1l   = (ushort*)(Wb + 24 * MBy);
    ushort* Hih   = (ushort*)(Wb + 80 * MBy);   // 32MB: 80-112
    ushort* Hil   = (ushort*)(Wb + 48 * MBy);   // 32MB: 48-80
    ushort* W2h   = (ushort*)(Wb + 16 * MBy);
    ushort* W2l   = (ushort*)(Wb + 24 * MBy);
    float*  Y0    = (float*)(Wb + 32 * MBy);
    float*  Y1    = (float*)d_out;              // scratch until final LN

    const int M = B_ * NQ_;
    const int n4act = M * D_ / 4;
    dim3 blk(256);
    dim3 gQKV(D_ / 128, M / 128, 3);
    dim3 gSK(D_ / 128, M / 128, 2);

    split_rows<<<n4act / 256, blk, 0, stream>>>(Q, Qh, Ql, n4act);
    split_rows<<<n4act / 256, blk, 0, stream>>>(K, Kh, Kl, n4act);
    split_tr<<<dim3(D_/32, D_/32), blk, 0, stream>>>(Wq, Wqh, Wql, D_, D_);
    split_tr<<<dim3(D_/32, D_/32), blk, 0, stream>>>(Wk, Wkh, Wkl, D_, D_);
    split_tr<<<dim3(D_/32, D_/32), blk, 0, stream>>>(Wv, Wvh, Wvl, D_, D_);
    split_tr<<<dim3(D_/32, D_/32), blk, 0, stream>>>(Wo, Woh, Wol, D_, D_);

    QkvArgs qa;
    qa.Ah[0] = Qh;  qa.Al[0] = Ql;  qa.Bh[0] = Wqh; qa.Bl[0] = Wql; qa.bias[0] = bq; qa.Co[0] = qhp;
    qa.Ah[1] = Kh;  qa.Al[1] = Kl;  qa.Bh[1] = Wkh; qa.Bl[1] = Wkl; qa.bias[1] = bk; qa.Co[1] = khp;
    qa.Ah[2] = Kh;  qa.Al[2] = Kl;  qa.Bh[2] = Wvh; qa.Bl[2] = Wvl; qa.bias[2] = bv; qa.Co[2] = vhp;
    gemm_qkv<<<gQKV, blk, 0, stream>>>(qa, M, D_, D_);

    flash_attn_mfma<<<dim3(1024), blk, 0, stream>>>(qhp, khp, vhp, aOh, aOl);

    gemm_splitk2<<<gSK, blk, 0, stream>>>(aOh, aOl, Woh, Wol, bo, oprj0, oprj1, M, D_, D_);
    add_ln3<true><<<M, blk, 0, stream>>>(oprj0, oprj1, Q, g0, be0, Xf, Xh, Xl);

    split_tr<<<dim3(DFF_/32, D_/32), blk, 0, stream>>>(W1, W1h, W1l, D_, DFF_);
    gemm_ffn1_256<<<dim3(DFF_/256, M/256), dim3(512), 0, stream>>>(
        Xh, Xl, W1h, W1l, b1, Hih, Hil, M, DFF_, D_);
    split_tr<<<dim3(D_/32, DFF_/32), blk, 0, stream>>>(W2, W2h, W2l, DFF_, D_);

    gemm_splitk2<<<gSK, blk, 0, stream>>>(Hih, Hil, W2h, W2l, b2, Y0, Y1, M, D_, DFF_);
    add_ln3<false><<<M, blk, 0, stream>>>(Y0, Y1, Xf, g1, be1, (float*)d_out, nullptr, nullptr);
}